// Round 9
// baseline (376.038 us; speedup 1.0000x reference)
//
#include <hip/hip_runtime.h>

#define N_NODES   100000
#define D_DIM     16
#define NFILT     8
#define KOUT      128
#define NNZ_CNT   1600000

// two-level binning geometry
#define SHIFT1    12
#define NC1       25                                   // coarse buckets (key>>12)
#define CAP1      67072                                // slots per coarse (mu 64000 + ~12 sigma)
#define NSUB      64                                   // sub-buckets per coarse
#define CROWS     64                                   // keys per final bucket
#define NCB       (NC1 * NSUB)                         // 1600 final buckets
#define CAP       1408                                 // final bucket slots (mu 1024 + ~12 sigma)
#define EPB       2048                                 // edges/records per bin block
#define NBLKA     ((NNZ_CNT + EPB - 1) / EPB)          // 782 coarse blocks
#define CHB       ((CAP1 + EPB - 1) / EPB)             // 33 chunks per coarse in binF
#define NWAVES    8                                    // waves per 512-thr block
#define CPAD      16                                   // ints per cursor = one 64B line

// combo[node] = 64B line: [0..7]=LTx bf16 pairs (u32), [8..11]=wav bf16 (u16 x8).

// fp32 -> bf16 bits with round-to-nearest-even (same as __float2bfloat16)
__device__ __forceinline__ uint f32_to_bf16_bits(float f) {
    uint u = __float_as_uint(f);
    uint r = (u + 0x7FFFu + ((u >> 16) & 1u)) >> 16;
    return r;
}

// w_wav[n,f] = t^(2^f) - t^(2^(f+1)); fp32 compute, bf16 store into combo[n][8..11]
__global__ void wav_kernel(const float* __restrict__ eig, uint* __restrict__ combo) {
    int n = blockIdx.x * blockDim.x + threadIdx.x;
    if (n >= N_NODES) return;
    float cur = expf(-eig[n]);
    uint pk[4];
#pragma unroll
    for (int h = 0; h < 4; ++h) {
        float nx0 = cur * cur;
        float w0 = cur - nx0;
        float nx1 = nx0 * nx0;
        float w1 = nx0 - nx1;
        cur = nx1;
        pk[h] = f32_to_bf16_bits(w0) | (f32_to_bf16_bits(w1) << 16);
    }
    *(uint4*)(combo + (size_t)n * 16 + 8) = make_uint4(pk[0], pk[1], pk[2], pk[3]);
}

// binC2: FUSED coarse binning for both orderings, with PER-WAVE SHARDED
// histograms/cursors. Round-4/8 lesson: same-address atomic chains serialize;
// the unsharded version did ~82 serialized LDS RMWs per counter per phase
// (hist + scatter, x2 orderings). Sharding by wave cuts chains 8x.
// Stages 2048 edges in registers ONCE. Runs ~82 rec = 656B -> coalesced
// copy-out (round-5 lesson: scattered 8B stores cost ~100MB of line RMW).
// Record: x = ((key & 4095) << 17) | payload   (12 key bits survive to binF).
__global__ __launch_bounds__(512) void binC2_kernel(const int* __restrict__ rows,
                                                    const int* __restrict__ cols,
                                                    const float* __restrict__ v,
                                                    int* __restrict__ gc1c,
                                                    int* __restrict__ gc1r,
                                                    int2* __restrict__ regBc,
                                                    int2* __restrict__ regBr) {
    __shared__ int hist[NWAVES * NC1];   // per-wave counts -> per-wave cursors
    __shared__ int cnt[NC1], offb[NC1], gbase[NC1];
    __shared__ int2 rec[EPB];
    __shared__ unsigned char rbk[EPB];
    int tid = threadIdx.x;
    int wv = tid >> 6;
    int e0 = blockIdx.x * EPB;
    int nE = NNZ_CNT - e0; if (nE > EPB) nE = EPB;

    int r_[4], c_[4], vb_[4];
    int nk = 0;
#pragma unroll
    for (int kk = 0; kk < 4; ++kk) {
        int i = tid + kk * 512;
        if (i < nE) {
            r_[kk] = rows[e0 + i];
            c_[kk] = cols[e0 + i];
            vb_[kk] = __float_as_int(v[e0 + i]);
            nk = kk + 1;
        }
    }

    // ---- phase A: key = col, payload = row -> regBc ----
    for (int i = tid; i < NWAVES * NC1; i += 512) hist[i] = 0;
    __syncthreads();
    for (int kk = 0; kk < nk; ++kk)
        atomicAdd(&hist[wv * NC1 + (c_[kk] >> SHIFT1)], 1);
    __syncthreads();
    if (tid < NC1) {
        int tot = 0;
        for (int w = 0; w < NWAVES; ++w) tot += hist[w * NC1 + tid];
        cnt[tid] = tot;
    }
    __syncthreads();
    if (tid == 0) { int run = 0; for (int b = 0; b < NC1; ++b) { offb[b] = run; run += cnt[b]; } }
    __syncthreads();
    if (tid < NC1) {
        gbase[tid] = cnt[tid] ? atomicAdd(&gc1c[tid * CPAD], cnt[tid]) : 0;
        int run = offb[tid];
        for (int w = 0; w < NWAVES; ++w) {       // per-wave cursor bases
            int h = hist[w * NC1 + tid];
            hist[w * NC1 + tid] = run;
            run += h;
        }
    }
    __syncthreads();
    for (int kk = 0; kk < nk; ++kk) {
        int b = c_[kk] >> SHIFT1;
        int pos = atomicAdd(&hist[wv * NC1 + b], 1);
        rec[pos] = make_int2(((c_[kk] & 4095) << 17) | r_[kk], vb_[kk]);
        rbk[pos] = (unsigned char)b;
    }
    __syncthreads();
    for (int i = tid; i < nE; i += 512) {
        int b = rbk[i];
        int slot = gbase[b] + (i - offb[b]);
        if (slot < CAP1) regBc[(size_t)b * CAP1 + slot] = rec[i];
    }
    __syncthreads();

    // ---- phase B: key = row, payload = col -> regBr ----
    for (int i = tid; i < NWAVES * NC1; i += 512) hist[i] = 0;
    __syncthreads();
    for (int kk = 0; kk < nk; ++kk)
        atomicAdd(&hist[wv * NC1 + (r_[kk] >> SHIFT1)], 1);
    __syncthreads();
    if (tid < NC1) {
        int tot = 0;
        for (int w = 0; w < NWAVES; ++w) tot += hist[w * NC1 + tid];
        cnt[tid] = tot;
    }
    __syncthreads();
    if (tid == 0) { int run = 0; for (int b = 0; b < NC1; ++b) { offb[b] = run; run += cnt[b]; } }
    __syncthreads();
    if (tid < NC1) {
        gbase[tid] = cnt[tid] ? atomicAdd(&gc1r[tid * CPAD], cnt[tid]) : 0;
        int run = offb[tid];
        for (int w = 0; w < NWAVES; ++w) {
            int h = hist[w * NC1 + tid];
            hist[w * NC1 + tid] = run;
            run += h;
        }
    }
    __syncthreads();
    for (int kk = 0; kk < nk; ++kk) {
        int b = r_[kk] >> SHIFT1;
        int pos = atomicAdd(&hist[wv * NC1 + b], 1);
        rec[pos] = make_int2(((r_[kk] & 4095) << 17) | c_[kk], vb_[kk]);
        rbk[pos] = (unsigned char)b;
    }
    __syncthreads();
    for (int i = tid; i < nE; i += 512) {
        int b = rbk[i];
        int slot = gbase[b] + (i - offb[b]);
        if (slot < CAP1) regBr[(size_t)b * CAP1 + slot] = rec[i];
    }
}

// binF: fine binning (UNCHANGED control). Block = one 2048-record chunk of
// one coarse bucket; bins into 64 sub-buckets (runs ~32 rec = 256B).
// sub = record bits 23..28. Output keeps 6 low key bits:
// x = (keylow6 << 17) | payload  (mask 0x7FFFFF).
__global__ __launch_bounds__(512) void binF_kernel(const int* __restrict__ gcur1,
                                                   const int2* __restrict__ regB,
                                                   int* __restrict__ gcurF,
                                                   int2* __restrict__ regA) {
    __shared__ int cnt[NSUB], offb[NSUB], gbase[NSUB], cur[NSUB];
    __shared__ int2 rec[EPB];
    __shared__ unsigned char rbk[EPB];
    int tid = threadIdx.x;
    int cb = blockIdx.x / CHB;
    int ch = blockIdx.x % CHB;
    int nc = gcur1[cb * CPAD]; if (nc > CAP1) nc = CAP1;
    int cs = ch * EPB;
    if (cs >= nc) return;                 // uniform early-exit
    int nE = nc - cs; if (nE > EPB) nE = EPB;
    size_t srcb = (size_t)cb * CAP1 + cs;

    if (tid < NSUB) cnt[tid] = 0;
    __syncthreads();

    int2 my[4]; int msub[4];
    int nk = 0;
#pragma unroll
    for (int kk = 0; kk < 4; ++kk) {
        int i = tid + kk * 512;
        msub[kk] = -1;
        if (i < nE) {
            my[kk] = regB[srcb + i];
            msub[kk] = (my[kk].x >> 23) & (NSUB - 1);
            nk = kk + 1;
            atomicAdd(&cnt[msub[kk]], 1);
        }
    }
    __syncthreads();

    if (tid == 0) { int run = 0; for (int b = 0; b < NSUB; ++b) { offb[b] = run; run += cnt[b]; } }
    __syncthreads();
    if (tid < NSUB) {
        gbase[tid] = cnt[tid] ? atomicAdd(&gcurF[(cb * NSUB + tid) * CPAD], cnt[tid]) : 0;
        cur[tid] = offb[tid];
    }
    __syncthreads();

    for (int kk = 0; kk < nk; ++kk)
        if (msub[kk] >= 0) {
            int pos = atomicAdd(&cur[msub[kk]], 1);
            rec[pos] = make_int2(my[kk].x & 0x7FFFFF, my[kk].y);  // keylow(6) | payload(17)
            rbk[pos] = (unsigned char)msub[kk];
        }
    __syncthreads();

    for (int i = tid; i < nE; i += 512) {
        int b = rbk[i];
        int slot = gbase[b] + (i - offb[b]);
        if (slot < CAP)
            regA[(size_t)(cb * NSUB + b) * CAP + slot] = rec[i];
    }
}

// Pass 1, SORT-FREE: one block per COLUMN bucket (64 cols, 256 thr).
// A segment-sum needs no ordering: stage the bucket's records into LDS
// (coalesced, unsorted), then 4 records/wave-iter -- 16 lanes per record
// read x[r][0..15] (one 64B line, coalesced) and ds_add_f32 into a 64x16
// fp32 LDS accumulator. No histogram/scan/scatter/shfl; iterations carry no
// dependency (fire-and-forget adds) so the rec->x->add chain pipelines.
// Finally pack bf16 pairs {d,d+8} into combo[c][0..7].
__global__ __launch_bounds__(256) void sg1_nosort_kernel(const int* __restrict__ gcurF,
                                                         const int2* __restrict__ regA,
                                                         const float* __restrict__ x,
                                                         uint* __restrict__ combo) {
    __shared__ float acc[CROWS * D_DIM];   // 4 KB
    __shared__ int2 rec[CAP];              // 11 KB
    int tid = threadIdx.x;
    int b = blockIdx.x;
    int nb = gcurF[b * CPAD]; if (nb > CAP) nb = CAP;
    size_t base = (size_t)b * CAP;

    for (int t = tid; t < CROWS * D_DIM; t += 256) acc[t] = 0.f;
    for (int i = tid; i < nb; i += 256) rec[i] = regA[base + i];
    __syncthreads();

    int wv = tid >> 6, lane = tid & 63;
    int sub = lane >> 4;       // record slot 0..3 within the wave
    int d = lane & 15;         // feature dim
    for (int i = (wv << 2) + sub; i < nb; i += 16) {
        int2 e = rec[i];                       // 16-lane LDS broadcast
        int cl = e.x >> 17;
        int r  = e.x & 0x1FFFF;
        atomicAdd(&acc[(cl << 4) + d],
                  __int_as_float(e.y) * x[(size_t)r * D_DIM + d]);
    }
    __syncthreads();

    for (int t = tid; t < CROWS * NFILT; t += 256) {
        int cl = t >> 3, j = t & 7;
        int c = b * CROWS + cl;
        if (c < N_NODES)
            combo[(size_t)c * 16 + j] =
                f32_to_bf16_bits(acc[(cl << 4) + j]) |
                (f32_to_bf16_bits(acc[(cl << 4) + j + 8]) << 16);
    }
}

// Fused sort+gather for pass 2 (UNCHANGED control; one block per ROW bucket,
// 64 rows, 256 thr). Reg-staged LDS sort; gather reads ONE combo line per
// record (LTx pairs + wav in the same 64B). out stores nontemporal: 51 MB of
// write-once lines must not evict the combo working set.
__global__ __launch_bounds__(256) void sortgather2_kernel(const int* __restrict__ gcurF,
                                                          const int2* __restrict__ regA,
                                                          const uint* __restrict__ combo,
                                                          float* __restrict__ out) {
    __shared__ int2 rec[CAP];        // 11 KB, row-sorted: (col, vbits)
    __shared__ int cnt[CROWS], sc[CROWS], st[CROWS], cur[CROWS];
    int tid = threadIdx.x;
    int b = blockIdx.x;
    int nb = gcurF[b * CPAD]; if (nb > CAP) nb = CAP;
    size_t base = (size_t)b * CAP;

    int2 my[6]; int mkey[6];
    if (tid < CROWS) cnt[tid] = 0;
    __syncthreads();
#pragma unroll
    for (int s = 0; s < 6; ++s) {
        int i = tid + s * 256;
        mkey[s] = -1;
        if (i < nb) {
            my[s] = regA[base + i];
            mkey[s] = my[s].x >> 17;
            atomicAdd(&cnt[mkey[s]], 1);
        }
    }
    __syncthreads();

    int cv = (tid < CROWS) ? cnt[tid] : 0;
    if (tid < CROWS) sc[tid] = cv;
    __syncthreads();
    for (int off = 1; off < CROWS; off <<= 1) {
        int t = (tid < CROWS && tid >= off) ? sc[tid - off] : 0;
        __syncthreads();
        if (tid < CROWS) sc[tid] += t;
        __syncthreads();
    }
    if (tid < CROWS) { int s0 = sc[tid] - cv; st[tid] = s0; cur[tid] = s0; }
    __syncthreads();

#pragma unroll
    for (int s = 0; s < 6; ++s)
        if (mkey[s] >= 0) {
            int pos = atomicAdd(&cur[mkey[s]], 1);
            if (pos < CAP) rec[pos] = make_int2(my[s].x & 0x1FFFF, my[s].y);
        }
    __syncthreads();

    // gather: 4 waves x 16 rows; lane owns outputs (lane) and (lane+64)
    int wave = tid >> 6, lane = tid & 63;
    int d0 = lane >> 3;        // pair index 0..7
    int f  = lane & 7;         // 0..7
    for (int rl = wave; rl < CROWS; rl += 4) {
        int row = b * CROWS + rl;
        if (row >= N_NODES) continue;
        int i = st[rl], end = st[rl] + cnt[rl]; if (end > CAP) end = CAP;
        float acc0 = 0.f, acc1 = 0.f;
        for (; i + 4 <= end; i += 4) {
            int2 e0 = rec[i], e1 = rec[i + 1], e2 = rec[i + 2], e3 = rec[i + 3];
            uint l0 = combo[(size_t)e0.x * 16 + d0];
            uint l1 = combo[(size_t)e1.x * 16 + d0];
            uint l2 = combo[(size_t)e2.x * 16 + d0];
            uint l3 = combo[(size_t)e3.x * 16 + d0];
            uint w0 = ((const ushort*)(combo + (size_t)e0.x * 16 + 8))[f];
            uint w1 = ((const ushort*)(combo + (size_t)e1.x * 16 + 8))[f];
            uint w2 = ((const ushort*)(combo + (size_t)e2.x * 16 + 8))[f];
            uint w3 = ((const ushort*)(combo + (size_t)e3.x * 16 + 8))[f];
            float vw0 = __int_as_float(e0.y) * __uint_as_float(w0 << 16);
            float vw1 = __int_as_float(e1.y) * __uint_as_float(w1 << 16);
            float vw2 = __int_as_float(e2.y) * __uint_as_float(w2 << 16);
            float vw3 = __int_as_float(e3.y) * __uint_as_float(w3 << 16);
            acc0 = fmaf(vw0, __uint_as_float(l0 << 16), acc0);
            acc1 = fmaf(vw0, __uint_as_float(l0 & 0xFFFF0000u), acc1);
            acc0 = fmaf(vw1, __uint_as_float(l1 << 16), acc0);
            acc1 = fmaf(vw1, __uint_as_float(l1 & 0xFFFF0000u), acc1);
            acc0 = fmaf(vw2, __uint_as_float(l2 << 16), acc0);
            acc1 = fmaf(vw2, __uint_as_float(l2 & 0xFFFF0000u), acc1);
            acc0 = fmaf(vw3, __uint_as_float(l3 << 16), acc0);
            acc1 = fmaf(vw3, __uint_as_float(l3 & 0xFFFF0000u), acc1);
        }
        for (; i < end; ++i) {
            int2 e = rec[i];
            uint l = combo[(size_t)e.x * 16 + d0];
            uint w = ((const ushort*)(combo + (size_t)e.x * 16 + 8))[f];
            float vw = __int_as_float(e.y) * __uint_as_float(w << 16);
            acc0 = fmaf(vw, __uint_as_float(l << 16), acc0);
            acc1 = fmaf(vw, __uint_as_float(l & 0xFFFF0000u), acc1);
        }
        __builtin_nontemporal_store(acc0, &out[(size_t)row * KOUT + lane]);
        __builtin_nontemporal_store(acc1, &out[(size_t)row * KOUT + 64 + lane]);
    }
}

extern "C" void kernel_launch(void* const* d_in, const int* in_sizes, int n_in,
                              void* d_out, int out_size, void* d_ws, size_t ws_size,
                              hipStream_t stream) {
    const float* x      = (const float*)d_in[0];
    const int*   L_rows = (const int*)  d_in[1];
    const int*   L_cols = (const int*)  d_in[2];
    const float* L_v    = (const float*)d_in[3];
    const float* eig    = (const float*)d_in[4];
    float* out = (float*)d_out;

    // workspace layout (~51.5 MB): combo 6.4 + regBc/regBr 13.4 each +
    // regA 18.0 + cursors 0.2. regA reused across passes (stream-ordered).
    uint* combo = (uint*)d_ws;                                // [N*16]      6.4 MB (64B/node)
    int2* regBc = (int2*)(combo + (size_t)N_NODES * 16);      // [NC1*CAP1] 13.4 MB
    int2* regBr = regBc + (size_t)NC1 * CAP1;                 // [NC1*CAP1] 13.4 MB
    int2* regA  = regBr + (size_t)NC1 * CAP1;                 // [NCB*CAP]  18.0 MB
    int*  gc1c  = (int*)(regA + (size_t)NCB * CAP);           // coarse cursors (col)
    int*  gc1r  = gc1c + NC1 * CPAD;                          // coarse cursors (row)
    int*  gfc   = gc1r + NC1 * CPAD;                          // final cursors (col)
    int*  gfr   = gfc + NCB * CPAD;                           // final cursors (row)

    hipMemsetAsync(gc1c, 0, (size_t)(2 * NC1 + 2 * NCB) * CPAD * sizeof(int), stream);

    wav_kernel<<<(N_NODES + 255) / 256, 256, 0, stream>>>(eig, combo);

    // Fused coarse binning: edges read once, both orderings produced
    binC2_kernel<<<NBLKA, 512, 0, stream>>>(L_rows, L_cols, L_v, gc1c, gc1r, regBc, regBr);

    // Pass 1: COLUMN ordering (fine bin -> sort-free LDS accumulate -> combo LTx)
    binF_kernel<<<NC1 * CHB, 512, 0, stream>>>(gc1c, regBc, gfc, regA);
    sg1_nosort_kernel<<<NCB, 256, 0, stream>>>(gfc, regA, x, combo);

    // Pass 2: ROW ordering (reusing regA)
    binF_kernel<<<NC1 * CHB, 512, 0, stream>>>(gc1r, regBr, gfr, regA);
    sortgather2_kernel<<<NCB, 256, 0, stream>>>(gfr, regA, combo, out);
}

// Round 10
// 284.758 us; speedup vs baseline: 1.3206x; 1.3206x over previous
//
#include <hip/hip_runtime.h>

#define N_NODES   100000
#define D_DIM     16
#define NFILT     8
#define KOUT      128
#define NNZ_CNT   1600000

// two-level binning geometry
#define SHIFT1    12
#define NC1       25                                   // coarse buckets (key>>12)
#define CAP1      67072                                // slots per coarse (mu 64000 + ~12 sigma)
#define NSUB      64                                   // sub-buckets per coarse
#define CROWS     64                                   // keys per final bucket
#define NCB       (NC1 * NSUB)                         // 1600 final buckets
#define CAP       1408                                 // final bucket slots (mu 1024 + ~12 sigma)
#define EPB       2048                                 // edges/records per bin block
#define NBLKA     ((NNZ_CNT + EPB - 1) / EPB)          // 782 coarse blocks
#define CHB       ((CAP1 + EPB - 1) / EPB)             // 33 chunks per coarse in binF
#define NWAVES    8                                    // waves per 512-thr block
#define CPAD      16                                   // ints per cursor = one 64B line

// fp32 -> bf16 bits with round-to-nearest-even (same as __float2bfloat16)
__device__ __forceinline__ uint f32_to_bf16_bits(float f) {
    uint u = __float_as_uint(f);
    uint r = (u + 0x7FFFu + ((u >> 16) & 1u)) >> 16;
    return r;
}

// w_wav[n,f] = t^(2^f) - t^(2^(f+1)); fp32 compute, bf16 store (RNE)
__global__ void wav_kernel(const float* __restrict__ eig, ushort* __restrict__ wavb) {
    int n = blockIdx.x * blockDim.x + threadIdx.x;
    if (n >= N_NODES) return;
    float cur = expf(-eig[n]);
    uint pk[4];
#pragma unroll
    for (int h = 0; h < 4; ++h) {
        float nx0 = cur * cur;
        float w0 = cur - nx0;
        float nx1 = nx0 * nx0;
        float w1 = nx0 - nx1;
        cur = nx1;
        pk[h] = f32_to_bf16_bits(w0) | (f32_to_bf16_bits(w1) << 16);
    }
    *(uint4*)(wavb + (size_t)n * NFILT) = make_uint4(pk[0], pk[1], pk[2], pk[3]);
}

// binC2: FUSED coarse binning for both orderings, with PER-WAVE SHARDED
// histograms/cursors (round-4/8 lesson: same-address atomic chains serialize;
// unsharded = ~82-deep LDS RMW chains per counter per phase, x2 orderings;
// sharding by wave cuts chains 8x). Stages 2048 edges in registers ONCE.
// Runs ~82 rec = 656B -> coalesced copy-out (round-5 lesson: scattered 8B
// stores cost ~100MB of line RMW).
// Record: x = ((key & 4095) << 17) | payload   (12 key bits survive to binF).
__global__ __launch_bounds__(512) void binC2_kernel(const int* __restrict__ rows,
                                                    const int* __restrict__ cols,
                                                    const float* __restrict__ v,
                                                    int* __restrict__ gc1c,
                                                    int* __restrict__ gc1r,
                                                    int2* __restrict__ regBc,
                                                    int2* __restrict__ regBr) {
    __shared__ int hist[NWAVES * NC1];   // per-wave counts -> per-wave cursors
    __shared__ int cnt[NC1], offb[NC1], gbase[NC1];
    __shared__ int2 rec[EPB];
    __shared__ unsigned char rbk[EPB];
    int tid = threadIdx.x;
    int wv = tid >> 6;
    int e0 = blockIdx.x * EPB;
    int nE = NNZ_CNT - e0; if (nE > EPB) nE = EPB;

    int r_[4], c_[4], vb_[4];
    int nk = 0;
#pragma unroll
    for (int kk = 0; kk < 4; ++kk) {
        int i = tid + kk * 512;
        if (i < nE) {
            r_[kk] = rows[e0 + i];
            c_[kk] = cols[e0 + i];
            vb_[kk] = __float_as_int(v[e0 + i]);
            nk = kk + 1;
        }
    }

    // ---- phase A: key = col, payload = row -> regBc ----
    for (int i = tid; i < NWAVES * NC1; i += 512) hist[i] = 0;
    __syncthreads();
    for (int kk = 0; kk < nk; ++kk)
        atomicAdd(&hist[wv * NC1 + (c_[kk] >> SHIFT1)], 1);
    __syncthreads();
    if (tid < NC1) {
        int tot = 0;
        for (int w = 0; w < NWAVES; ++w) tot += hist[w * NC1 + tid];
        cnt[tid] = tot;
    }
    __syncthreads();
    if (tid == 0) { int run = 0; for (int b = 0; b < NC1; ++b) { offb[b] = run; run += cnt[b]; } }
    __syncthreads();
    if (tid < NC1) {
        gbase[tid] = cnt[tid] ? atomicAdd(&gc1c[tid * CPAD], cnt[tid]) : 0;
        int run = offb[tid];
        for (int w = 0; w < NWAVES; ++w) {       // per-wave cursor bases
            int h = hist[w * NC1 + tid];
            hist[w * NC1 + tid] = run;
            run += h;
        }
    }
    __syncthreads();
    for (int kk = 0; kk < nk; ++kk) {
        int b = c_[kk] >> SHIFT1;
        int pos = atomicAdd(&hist[wv * NC1 + b], 1);
        rec[pos] = make_int2(((c_[kk] & 4095) << 17) | r_[kk], vb_[kk]);
        rbk[pos] = (unsigned char)b;
    }
    __syncthreads();
    for (int i = tid; i < nE; i += 512) {
        int b = rbk[i];
        int slot = gbase[b] + (i - offb[b]);
        if (slot < CAP1) regBc[(size_t)b * CAP1 + slot] = rec[i];
    }
    __syncthreads();

    // ---- phase B: key = row, payload = col -> regBr ----
    for (int i = tid; i < NWAVES * NC1; i += 512) hist[i] = 0;
    __syncthreads();
    for (int kk = 0; kk < nk; ++kk)
        atomicAdd(&hist[wv * NC1 + (r_[kk] >> SHIFT1)], 1);
    __syncthreads();
    if (tid < NC1) {
        int tot = 0;
        for (int w = 0; w < NWAVES; ++w) tot += hist[w * NC1 + tid];
        cnt[tid] = tot;
    }
    __syncthreads();
    if (tid == 0) { int run = 0; for (int b = 0; b < NC1; ++b) { offb[b] = run; run += cnt[b]; } }
    __syncthreads();
    if (tid < NC1) {
        gbase[tid] = cnt[tid] ? atomicAdd(&gc1r[tid * CPAD], cnt[tid]) : 0;
        int run = offb[tid];
        for (int w = 0; w < NWAVES; ++w) {
            int h = hist[w * NC1 + tid];
            hist[w * NC1 + tid] = run;
            run += h;
        }
    }
    __syncthreads();
    for (int kk = 0; kk < nk; ++kk) {
        int b = r_[kk] >> SHIFT1;
        int pos = atomicAdd(&hist[wv * NC1 + b], 1);
        rec[pos] = make_int2(((r_[kk] & 4095) << 17) | c_[kk], vb_[kk]);
        rbk[pos] = (unsigned char)b;
    }
    __syncthreads();
    for (int i = tid; i < nE; i += 512) {
        int b = rbk[i];
        int slot = gbase[b] + (i - offb[b]);
        if (slot < CAP1) regBr[(size_t)b * CAP1 + slot] = rec[i];
    }
}

// binF: fine binning (UNCHANGED control). Block = one 2048-record chunk of
// one coarse bucket; bins into 64 sub-buckets (runs ~32 rec = 256B).
// sub = record bits 23..28. Output keeps 6 low key bits:
// x = (keylow6 << 17) | payload  (mask 0x7FFFFF).
__global__ __launch_bounds__(512) void binF_kernel(const int* __restrict__ gcur1,
                                                   const int2* __restrict__ regB,
                                                   int* __restrict__ gcurF,
                                                   int2* __restrict__ regA) {
    __shared__ int cnt[NSUB], offb[NSUB], gbase[NSUB], cur[NSUB];
    __shared__ int2 rec[EPB];
    __shared__ unsigned char rbk[EPB];
    int tid = threadIdx.x;
    int cb = blockIdx.x / CHB;
    int ch = blockIdx.x % CHB;
    int nc = gcur1[cb * CPAD]; if (nc > CAP1) nc = CAP1;
    int cs = ch * EPB;
    if (cs >= nc) return;                 // uniform early-exit
    int nE = nc - cs; if (nE > EPB) nE = EPB;
    size_t srcb = (size_t)cb * CAP1 + cs;

    if (tid < NSUB) cnt[tid] = 0;
    __syncthreads();

    int2 my[4]; int msub[4];
    int nk = 0;
#pragma unroll
    for (int kk = 0; kk < 4; ++kk) {
        int i = tid + kk * 512;
        msub[kk] = -1;
        if (i < nE) {
            my[kk] = regB[srcb + i];
            msub[kk] = (my[kk].x >> 23) & (NSUB - 1);
            nk = kk + 1;
            atomicAdd(&cnt[msub[kk]], 1);
        }
    }
    __syncthreads();

    if (tid == 0) { int run = 0; for (int b = 0; b < NSUB; ++b) { offb[b] = run; run += cnt[b]; } }
    __syncthreads();
    if (tid < NSUB) {
        gbase[tid] = cnt[tid] ? atomicAdd(&gcurF[(cb * NSUB + tid) * CPAD], cnt[tid]) : 0;
        cur[tid] = offb[tid];
    }
    __syncthreads();

    for (int kk = 0; kk < nk; ++kk)
        if (msub[kk] >= 0) {
            int pos = atomicAdd(&cur[msub[kk]], 1);
            rec[pos] = make_int2(my[kk].x & 0x7FFFFF, my[kk].y);  // keylow(6) | payload(17)
            rbk[pos] = (unsigned char)msub[kk];
        }
    __syncthreads();

    for (int i = tid; i < nE; i += 512) {
        int b = rbk[i];
        int slot = gbase[b] + (i - offb[b]);
        if (slot < CAP)
            regA[(size_t)(cb * NSUB + b) * CAP + slot] = rec[i];
    }
}

// Fused sort+gather for pass 1 (round-7 measured structure; one block per
// COLUMN bucket, 64 cols, 256 thr). Records -> registers + LDS histogram,
// scan 64, scatter into col-sorted LDS rec[]; then per column, 16-lane x
// 4-subgroup walk with REGISTER accumulator (two failed experiments confirm:
// broadcast-record + LDS-atomic accumulate is latency-bound at <5% VALUBusy),
// shfl reduce, pack bf16 pairs {d,d+8} into LTxP.
__global__ __launch_bounds__(256) void sortgather1_kernel(const int* __restrict__ gcurF,
                                                          const int2* __restrict__ regA,
                                                          const float* __restrict__ x,
                                                          uint* __restrict__ LTxP) {
    __shared__ int2 rec[CAP];        // 11 KB, col-sorted: (row, vbits)
    __shared__ int cnt[CROWS], sc[CROWS], st[CROWS], cur[CROWS];
    int tid = threadIdx.x;
    int b = blockIdx.x;
    int nb = gcurF[b * CPAD]; if (nb > CAP) nb = CAP;
    size_t base = (size_t)b * CAP;

    int2 my[6]; int mkey[6];
    if (tid < CROWS) cnt[tid] = 0;
    __syncthreads();
#pragma unroll
    for (int s = 0; s < 6; ++s) {
        int i = tid + s * 256;
        mkey[s] = -1;
        if (i < nb) {
            my[s] = regA[base + i];
            mkey[s] = my[s].x >> 17;
            atomicAdd(&cnt[mkey[s]], 1);
        }
    }
    __syncthreads();

    int cv = (tid < CROWS) ? cnt[tid] : 0;
    if (tid < CROWS) sc[tid] = cv;
    __syncthreads();
    for (int off = 1; off < CROWS; off <<= 1) {
        int t = (tid < CROWS && tid >= off) ? sc[tid - off] : 0;
        __syncthreads();
        if (tid < CROWS) sc[tid] += t;
        __syncthreads();
    }
    if (tid < CROWS) { int s0 = sc[tid] - cv; st[tid] = s0; cur[tid] = s0; }
    __syncthreads();

#pragma unroll
    for (int s = 0; s < 6; ++s)
        if (mkey[s] >= 0) {
            int pos = atomicAdd(&cur[mkey[s]], 1);
            if (pos < CAP) rec[pos] = make_int2(my[s].x & 0x1FFFF, my[s].y);
        }
    __syncthreads();

    // gather: 4 waves x 16 cols; lane = (j<<4)|d, 4 records in flight per col
    int wave = tid >> 6, lane = tid & 63;
    int d = lane & 15, j = lane >> 4;
    for (int cl = wave; cl < CROWS; cl += 4) {
        int c = b * CROWS + cl;
        int i0 = st[cl], e0 = i0 + cnt[cl]; if (e0 > CAP) e0 = CAP;
        float acc = 0.f;
        for (int i = i0 + j; i < e0; i += 4) {
            int2 e = rec[i];                         // 16-lane LDS broadcast
            acc = fmaf(__int_as_float(e.y), x[(size_t)e.x * D_DIM + d], acc);
        }
        acc += __shfl_xor(acc, 16);
        acc += __shfl_xor(acc, 32);
        float hi = __shfl_down(acc, 8);
        if (lane < 8 && c < N_NODES)
            LTxP[(size_t)c * NFILT + lane] =
                f32_to_bf16_bits(acc) | (f32_to_bf16_bits(hi) << 16);
    }
}

// Fused sort+gather for pass 2 (round-7 geometry: one block per ROW bucket,
// 64 rows, 256 thr) but SPLIT gather tables: LTxP 3.2MB + wavb 1.6MB
// (round 6->7 data: the 64B/node combo RAISED FETCH 44.5->50.7MB — padded
// layout overflows L2 worse than the packed 4.8MB pair). out stores
// nontemporal: 51 MB of write-once lines must not evict the working set.
__global__ __launch_bounds__(256) void sortgather2_kernel(const int* __restrict__ gcurF,
                                                          const int2* __restrict__ regA,
                                                          const uint* __restrict__ LTxP,
                                                          const ushort* __restrict__ wavb,
                                                          float* __restrict__ out) {
    __shared__ int2 rec[CAP];        // 11 KB, row-sorted: (col, vbits)
    __shared__ int cnt[CROWS], sc[CROWS], st[CROWS], cur[CROWS];
    int tid = threadIdx.x;
    int b = blockIdx.x;
    int nb = gcurF[b * CPAD]; if (nb > CAP) nb = CAP;
    size_t base = (size_t)b * CAP;

    int2 my[6]; int mkey[6];
    if (tid < CROWS) cnt[tid] = 0;
    __syncthreads();
#pragma unroll
    for (int s = 0; s < 6; ++s) {
        int i = tid + s * 256;
        mkey[s] = -1;
        if (i < nb) {
            my[s] = regA[base + i];
            mkey[s] = my[s].x >> 17;
            atomicAdd(&cnt[mkey[s]], 1);
        }
    }
    __syncthreads();

    int cv = (tid < CROWS) ? cnt[tid] : 0;
    if (tid < CROWS) sc[tid] = cv;
    __syncthreads();
    for (int off = 1; off < CROWS; off <<= 1) {
        int t = (tid < CROWS && tid >= off) ? sc[tid - off] : 0;
        __syncthreads();
        if (tid < CROWS) sc[tid] += t;
        __syncthreads();
    }
    if (tid < CROWS) { int s0 = sc[tid] - cv; st[tid] = s0; cur[tid] = s0; }
    __syncthreads();

#pragma unroll
    for (int s = 0; s < 6; ++s)
        if (mkey[s] >= 0) {
            int pos = atomicAdd(&cur[mkey[s]], 1);
            if (pos < CAP) rec[pos] = make_int2(my[s].x & 0x1FFFF, my[s].y);
        }
    __syncthreads();

    // gather: 4 waves x 16 rows; lane owns outputs (lane) and (lane+64)
    int wave = tid >> 6, lane = tid & 63;
    int d0 = lane >> 3;        // pair index 0..7
    int f  = lane & 7;         // 0..7
    for (int rl = wave; rl < CROWS; rl += 4) {
        int row = b * CROWS + rl;
        if (row >= N_NODES) continue;
        int i = st[rl], end = st[rl] + cnt[rl]; if (end > CAP) end = CAP;
        float acc0 = 0.f, acc1 = 0.f;
        for (; i + 4 <= end; i += 4) {
            int2 e0 = rec[i], e1 = rec[i + 1], e2 = rec[i + 2], e3 = rec[i + 3];
            uint l0 = LTxP[e0.x * NFILT + d0];
            uint l1 = LTxP[e1.x * NFILT + d0];
            uint l2 = LTxP[e2.x * NFILT + d0];
            uint l3 = LTxP[e3.x * NFILT + d0];
            uint w0 = wavb[e0.x * NFILT + f];
            uint w1 = wavb[e1.x * NFILT + f];
            uint w2 = wavb[e2.x * NFILT + f];
            uint w3 = wavb[e3.x * NFILT + f];
            float vw0 = __int_as_float(e0.y) * __uint_as_float(w0 << 16);
            float vw1 = __int_as_float(e1.y) * __uint_as_float(w1 << 16);
            float vw2 = __int_as_float(e2.y) * __uint_as_float(w2 << 16);
            float vw3 = __int_as_float(e3.y) * __uint_as_float(w3 << 16);
            acc0 = fmaf(vw0, __uint_as_float(l0 << 16), acc0);
            acc1 = fmaf(vw0, __uint_as_float(l0 & 0xFFFF0000u), acc1);
            acc0 = fmaf(vw1, __uint_as_float(l1 << 16), acc0);
            acc1 = fmaf(vw1, __uint_as_float(l1 & 0xFFFF0000u), acc1);
            acc0 = fmaf(vw2, __uint_as_float(l2 << 16), acc0);
            acc1 = fmaf(vw2, __uint_as_float(l2 & 0xFFFF0000u), acc1);
            acc0 = fmaf(vw3, __uint_as_float(l3 << 16), acc0);
            acc1 = fmaf(vw3, __uint_as_float(l3 & 0xFFFF0000u), acc1);
        }
        for (; i < end; ++i) {
            int2 e = rec[i];
            uint l = LTxP[e.x * NFILT + d0];
            uint w = wavb[e.x * NFILT + f];
            float vw = __int_as_float(e.y) * __uint_as_float(w << 16);
            acc0 = fmaf(vw, __uint_as_float(l << 16), acc0);
            acc1 = fmaf(vw, __uint_as_float(l & 0xFFFF0000u), acc1);
        }
        __builtin_nontemporal_store(acc0, &out[(size_t)row * KOUT + lane]);
        __builtin_nontemporal_store(acc1, &out[(size_t)row * KOUT + 64 + lane]);
    }
}

extern "C" void kernel_launch(void* const* d_in, const int* in_sizes, int n_in,
                              void* d_out, int out_size, void* d_ws, size_t ws_size,
                              hipStream_t stream) {
    const float* x      = (const float*)d_in[0];
    const int*   L_rows = (const int*)  d_in[1];
    const int*   L_cols = (const int*)  d_in[2];
    const float* L_v    = (const float*)d_in[3];
    const float* eig    = (const float*)d_in[4];
    float* out = (float*)d_out;

    // workspace layout (~49.8 MB): LTxP 3.2 + wavb 1.6 + regBc/regBr 13.4
    // each + regA 18.0 + cursors 0.2. regA reused across passes.
    uint*   LTxP = (uint*)d_ws;                               // [N*8]       3.2 MB (bf16 pairs)
    ushort* wavb = (ushort*)(LTxP + (size_t)N_NODES * NFILT); // [N*8]       1.6 MB (bf16)
    int2*   regBc = (int2*)(wavb + (size_t)N_NODES * NFILT);  // [NC1*CAP1] 13.4 MB
    int2*   regBr = regBc + (size_t)NC1 * CAP1;               // [NC1*CAP1] 13.4 MB
    int2*   regA  = regBr + (size_t)NC1 * CAP1;               // [NCB*CAP]  18.0 MB
    int*    gc1c  = (int*)(regA + (size_t)NCB * CAP);         // coarse cursors (col)
    int*    gc1r  = gc1c + NC1 * CPAD;                        // coarse cursors (row)
    int*    gfc   = gc1r + NC1 * CPAD;                        // final cursors (col)
    int*    gfr   = gfc + NCB * CPAD;                         // final cursors (row)

    hipMemsetAsync(gc1c, 0, (size_t)(2 * NC1 + 2 * NCB) * CPAD * sizeof(int), stream);

    wav_kernel<<<(N_NODES + 255) / 256, 256, 0, stream>>>(eig, wavb);

    // Fused coarse binning (sharded hist): edges read once, both orderings
    binC2_kernel<<<NBLKA, 512, 0, stream>>>(L_rows, L_cols, L_v, gc1c, gc1r, regBc, regBr);

    // Pass 1: COLUMN ordering (fine bin -> fused sort+gather -> bf16 LTxP)
    binF_kernel<<<NC1 * CHB, 512, 0, stream>>>(gc1c, regBc, gfc, regA);
    sortgather1_kernel<<<NCB, 256, 0, stream>>>(gfc, regA, x, LTxP);

    // Pass 2: ROW ordering (reusing regA)
    binF_kernel<<<NC1 * CHB, 512, 0, stream>>>(gc1r, regBr, gfr, regA);
    sortgather2_kernel<<<NCB, 256, 0, stream>>>(gfr, regA, LTxP, wavb, out);
}

// Round 12
// 271.938 us; speedup vs baseline: 1.3828x; 1.0471x over previous
//
#include <hip/hip_runtime.h>

#define N_NODES   100000
#define D_DIM     16
#define NFILT     8
#define KOUT      128
#define NNZ_CNT   1600000

// two-level binning geometry
#define SHIFT1    12
#define NC1       25                                   // coarse buckets (key>>12)
#define CAP1      67072                                // slots per coarse (mu 64000 + ~12 sigma)
#define NSUB      64                                   // sub-buckets per coarse
#define CROWS     64                                   // keys per final bucket
#define NCB       (NC1 * NSUB)                         // 1600 final buckets
#define CAP       1408                                 // final bucket slots (mu 1024 + ~12 sigma)
#define EPB       2048                                 // edges/records per bin block
#define NBLKA     ((NNZ_CNT + EPB - 1) / EPB)          // 782 coarse blocks
#define CHB       ((CAP1 + EPB - 1) / EPB)             // 33 chunks per coarse in binF
#define CPAD      16                                   // ints per cursor = one 64B line

// combo[node] = 64B line: [0..7]=LTx bf16 pairs (u32), [8..11]=wav bf16 (u16 x8).
// R10 lesson: combo beats split tables — the wav load is an L1 hit on the line
// the LTx load fetched (split = 2 independent L2 accesses; FETCH lower, dur worse).

// fp32 -> bf16 bits with round-to-nearest-even (same as __float2bfloat16)
__device__ __forceinline__ uint f32_to_bf16_bits(float f) {
    uint u = __float_as_uint(f);
    uint r = (u + 0x7FFFu + ((u >> 16) & 1u)) >> 16;
    return r;
}

// w_wav[n,f] = t^(2^f) - t^(2^(f+1)); fp32 compute, bf16 store into combo[n][8..11]
__global__ void wav_kernel(const float* __restrict__ eig, uint* __restrict__ combo) {
    int n = blockIdx.x * blockDim.x + threadIdx.x;
    if (n >= N_NODES) return;
    float cur = expf(-eig[n]);
    uint pk[4];
#pragma unroll
    for (int h = 0; h < 4; ++h) {
        float nx0 = cur * cur;
        float w0 = cur - nx0;
        float nx1 = nx0 * nx0;
        float w1 = nx0 - nx1;
        cur = nx1;
        pk[h] = f32_to_bf16_bits(w0) | (f32_to_bf16_bits(w1) << 16);
    }
    *(uint4*)(combo + (size_t)n * 16 + 8) = make_uint4(pk[0], pk[1], pk[2], pk[3]);
}

// binC2: FUSED coarse binning for both orderings (R7 measured-best version;
// R10 showed sharded histograms are net-neutral-to-negative here). Stages
// 2048 edges in registers ONCE, runs two phases (key=col -> regBc, key=row ->
// regBr). Runs ~82 rec = 656B -> coalesced copy-out (round-5 lesson:
// scattered 8B stores cost ~100MB of line RMW).
// Record: x = ((key & 4095) << 17) | payload   (12 key bits survive to binF).
__global__ __launch_bounds__(512) void binC2_kernel(const int* __restrict__ rows,
                                                    const int* __restrict__ cols,
                                                    const float* __restrict__ v,
                                                    int* __restrict__ gc1c,
                                                    int* __restrict__ gc1r,
                                                    int2* __restrict__ regBc,
                                                    int2* __restrict__ regBr) {
    __shared__ int cnt[NC1], offb[NC1], gbase[NC1], cur[NC1];
    __shared__ int2 rec[EPB];
    __shared__ unsigned char rbk[EPB];
    int tid = threadIdx.x;
    int e0 = blockIdx.x * EPB;
    int nE = NNZ_CNT - e0; if (nE > EPB) nE = EPB;

    int r_[4], c_[4], vb_[4];
    int nk = 0;
#pragma unroll
    for (int kk = 0; kk < 4; ++kk) {
        int i = tid + kk * 512;
        if (i < nE) {
            r_[kk] = rows[e0 + i];
            c_[kk] = cols[e0 + i];
            vb_[kk] = __float_as_int(v[e0 + i]);
            nk = kk + 1;
        }
    }

    // ---- phase A: key = col, payload = row -> regBc ----
    if (tid < NC1) cnt[tid] = 0;
    __syncthreads();
    for (int kk = 0; kk < nk; ++kk) atomicAdd(&cnt[c_[kk] >> SHIFT1], 1);
    __syncthreads();
    if (tid == 0) { int run = 0; for (int b = 0; b < NC1; ++b) { offb[b] = run; run += cnt[b]; } }
    __syncthreads();
    if (tid < NC1) {
        gbase[tid] = cnt[tid] ? atomicAdd(&gc1c[tid * CPAD], cnt[tid]) : 0;
        cur[tid] = offb[tid];
    }
    __syncthreads();
    for (int kk = 0; kk < nk; ++kk) {
        int b = c_[kk] >> SHIFT1;
        int pos = atomicAdd(&cur[b], 1);
        rec[pos] = make_int2(((c_[kk] & 4095) << 17) | r_[kk], vb_[kk]);
        rbk[pos] = (unsigned char)b;
    }
    __syncthreads();
    for (int i = tid; i < nE; i += 512) {
        int b = rbk[i];
        int slot = gbase[b] + (i - offb[b]);
        if (slot < CAP1) regBc[(size_t)b * CAP1 + slot] = rec[i];
    }
    __syncthreads();

    // ---- phase B: key = row, payload = col -> regBr ----
    if (tid < NC1) cnt[tid] = 0;
    __syncthreads();
    for (int kk = 0; kk < nk; ++kk) atomicAdd(&cnt[r_[kk] >> SHIFT1], 1);
    __syncthreads();
    if (tid == 0) { int run = 0; for (int b = 0; b < NC1; ++b) { offb[b] = run; run += cnt[b]; } }
    __syncthreads();
    if (tid < NC1) {
        gbase[tid] = cnt[tid] ? atomicAdd(&gc1r[tid * CPAD], cnt[tid]) : 0;
        cur[tid] = offb[tid];
    }
    __syncthreads();
    for (int kk = 0; kk < nk; ++kk) {
        int b = r_[kk] >> SHIFT1;
        int pos = atomicAdd(&cur[b], 1);
        rec[pos] = make_int2(((r_[kk] & 4095) << 17) | c_[kk], vb_[kk]);
        rbk[pos] = (unsigned char)b;
    }
    __syncthreads();
    for (int i = tid; i < nE; i += 512) {
        int b = rbk[i];
        int slot = gbase[b] + (i - offb[b]);
        if (slot < CAP1) regBr[(size_t)b * CAP1 + slot] = rec[i];
    }
}

// binF: fine binning (unchanged control). Block = one 2048-record chunk of
// one coarse bucket; bins into 64 sub-buckets (runs ~32 rec = 256B).
// sub = record bits 23..28. Output keeps 6 low key bits:
// x = (keylow6 << 17) | payload  (mask 0x7FFFFF).
__global__ __launch_bounds__(512) void binF_kernel(const int* __restrict__ gcur1,
                                                   const int2* __restrict__ regB,
                                                   int* __restrict__ gcurF,
                                                   int2* __restrict__ regA) {
    __shared__ int cnt[NSUB], offb[NSUB], gbase[NSUB], cur[NSUB];
    __shared__ int2 rec[EPB];
    __shared__ unsigned char rbk[EPB];
    int tid = threadIdx.x;
    int cb = blockIdx.x / CHB;
    int ch = blockIdx.x % CHB;
    int nc = gcur1[cb * CPAD]; if (nc > CAP1) nc = CAP1;
    int cs = ch * EPB;
    if (cs >= nc) return;                 // uniform early-exit
    int nE = nc - cs; if (nE > EPB) nE = EPB;
    size_t srcb = (size_t)cb * CAP1 + cs;

    if (tid < NSUB) cnt[tid] = 0;
    __syncthreads();

    int2 my[4]; int msub[4];
    int nk = 0;
#pragma unroll
    for (int kk = 0; kk < 4; ++kk) {
        int i = tid + kk * 512;
        msub[kk] = -1;
        if (i < nE) {
            my[kk] = regB[srcb + i];
            msub[kk] = (my[kk].x >> 23) & (NSUB - 1);
            nk = kk + 1;
            atomicAdd(&cnt[msub[kk]], 1);
        }
    }
    __syncthreads();

    if (tid == 0) { int run = 0; for (int b = 0; b < NSUB; ++b) { offb[b] = run; run += cnt[b]; } }
    __syncthreads();
    if (tid < NSUB) {
        gbase[tid] = cnt[tid] ? atomicAdd(&gcurF[(cb * NSUB + tid) * CPAD], cnt[tid]) : 0;
        cur[tid] = offb[tid];
    }
    __syncthreads();

    for (int kk = 0; kk < nk; ++kk)
        if (msub[kk] >= 0) {
            int pos = atomicAdd(&cur[msub[kk]], 1);
            rec[pos] = make_int2(my[kk].x & 0x7FFFFF, my[kk].y);  // keylow(6) | payload(17)
            rbk[pos] = (unsigned char)msub[kk];
        }
    __syncthreads();

    for (int i = tid; i < nE; i += 512) {
        int b = rbk[i];
        int slot = gbase[b] + (i - offb[b]);
        if (slot < CAP)
            regA[(size_t)(cb * NSUB + b) * CAP + slot] = rec[i];
    }
}

// Fused sort+gather for pass 1 (one block per COLUMN bucket, 64 cols, 256
// thr). Records -> registers + LDS histogram, scan 64, scatter into
// col-sorted LDS rec[]; then per column, 16-lane x 4-subgroup walk with
// REGISTER accumulator, now UNROLLED x2 (8 loads in flight per wave — the
// gather phase was latency-exposed). shfl reduce, pack bf16 pairs {d,d+8}
// into combo[c][0..7]. Summation order unchanged (sequential records).
__global__ __launch_bounds__(256) void sortgather1_kernel(const int* __restrict__ gcurF,
                                                          const int2* __restrict__ regA,
                                                          const float* __restrict__ x,
                                                          uint* __restrict__ combo) {
    __shared__ int2 rec[CAP];        // 11.3 KB, col-sorted: (row, vbits)
    __shared__ int cnt[CROWS], sc[CROWS], st[CROWS], cur[CROWS];
    int tid = threadIdx.x;
    int b = blockIdx.x;
    int nb = gcurF[b * CPAD]; if (nb > CAP) nb = CAP;
    size_t base = (size_t)b * CAP;

    int2 my[6]; int mkey[6];
    if (tid < CROWS) cnt[tid] = 0;
    __syncthreads();
#pragma unroll
    for (int s = 0; s < 6; ++s) {
        int i = tid + s * 256;
        mkey[s] = -1;
        if (i < nb) {
            my[s] = regA[base + i];
            mkey[s] = my[s].x >> 17;
            atomicAdd(&cnt[mkey[s]], 1);
        }
    }
    __syncthreads();

    int cv = (tid < CROWS) ? cnt[tid] : 0;
    if (tid < CROWS) sc[tid] = cv;
    __syncthreads();
    for (int off = 1; off < CROWS; off <<= 1) {
        int t = (tid < CROWS && tid >= off) ? sc[tid - off] : 0;
        __syncthreads();
        if (tid < CROWS) sc[tid] += t;
        __syncthreads();
    }
    if (tid < CROWS) { int s0 = sc[tid] - cv; st[tid] = s0; cur[tid] = s0; }
    __syncthreads();

#pragma unroll
    for (int s = 0; s < 6; ++s)
        if (mkey[s] >= 0) {
            int pos = atomicAdd(&cur[mkey[s]], 1);
            if (pos < CAP) rec[pos] = make_int2(my[s].x & 0x1FFFF, my[s].y);
        }
    __syncthreads();

    // gather: 4 waves x 16 cols; lane = (j<<4)|d, unroll 2 (records i, i+4)
    int wave = tid >> 6, lane = tid & 63;
    int d = lane & 15, j = lane >> 4;
    for (int cl = wave; cl < CROWS; cl += 4) {
        int c = b * CROWS + cl;
        int i0 = st[cl], e0 = i0 + cnt[cl]; if (e0 > CAP) e0 = CAP;
        float acc = 0.f;
        int i = i0 + j;
        for (; i + 4 < e0; i += 8) {
            int2 ea = rec[i];
            int2 eb = rec[i + 4];
            float xa = x[(size_t)ea.x * D_DIM + d];
            float xb = x[(size_t)eb.x * D_DIM + d];
            acc = fmaf(__int_as_float(ea.y), xa, acc);
            acc = fmaf(__int_as_float(eb.y), xb, acc);
        }
        for (; i < e0; i += 4) {
            int2 e = rec[i];
            acc = fmaf(__int_as_float(e.y), x[(size_t)e.x * D_DIM + d], acc);
        }
        acc += __shfl_xor(acc, 16);
        acc += __shfl_xor(acc, 32);
        float hi = __shfl_down(acc, 8);
        if (lane < 8 && c < N_NODES)
            combo[(size_t)c * 16 + lane] =
                f32_to_bf16_bits(acc) | (f32_to_bf16_bits(hi) << 16);
    }
}

// Fused sort+gather for pass 2 (one block per ROW bucket, 64 rows, 256 thr).
// Reg-staged LDS sort; gather reads ONE combo line per record (wav is an L1
// hit on the LTx line). Gather now UNROLLED x8 (16 loads in flight; a
// 16-record row pays 2 latency exposures instead of 4 — VGPR headroom is
// free, grid-limited at ~25 waves/CU). Summation order unchanged. out
// stores nontemporal: 51 MB of write-once lines must not evict the combo
// working set.
__global__ __launch_bounds__(256) void sortgather2_kernel(const int* __restrict__ gcurF,
                                                          const int2* __restrict__ regA,
                                                          const uint* __restrict__ combo,
                                                          float* __restrict__ out) {
    __shared__ int2 rec[CAP];        // 11.3 KB, row-sorted: (col, vbits)
    __shared__ int cnt[CROWS], sc[CROWS], st[CROWS], cur[CROWS];
    int tid = threadIdx.x;
    int b = blockIdx.x;
    int nb = gcurF[b * CPAD]; if (nb > CAP) nb = CAP;
    size_t base = (size_t)b * CAP;

    int2 my[6]; int mkey[6];
    if (tid < CROWS) cnt[tid] = 0;
    __syncthreads();
#pragma unroll
    for (int s = 0; s < 6; ++s) {
        int i = tid + s * 256;
        mkey[s] = -1;
        if (i < nb) {
            my[s] = regA[base + i];
            mkey[s] = my[s].x >> 17;
            atomicAdd(&cnt[mkey[s]], 1);
        }
    }
    __syncthreads();

    int cv = (tid < CROWS) ? cnt[tid] : 0;
    if (tid < CROWS) sc[tid] = cv;
    __syncthreads();
    for (int off = 1; off < CROWS; off <<= 1) {
        int t = (tid < CROWS && tid >= off) ? sc[tid - off] : 0;
        __syncthreads();
        if (tid < CROWS) sc[tid] += t;
        __syncthreads();
    }
    if (tid < CROWS) { int s0 = sc[tid] - cv; st[tid] = s0; cur[tid] = s0; }
    __syncthreads();

#pragma unroll
    for (int s = 0; s < 6; ++s)
        if (mkey[s] >= 0) {
            int pos = atomicAdd(&cur[mkey[s]], 1);
            if (pos < CAP) rec[pos] = make_int2(my[s].x & 0x1FFFF, my[s].y);
        }
    __syncthreads();

    // gather: 4 waves x 16 rows; lane owns outputs (lane) and (lane+64)
    int wave = tid >> 6, lane = tid & 63;
    int d0 = lane >> 3;        // pair index 0..7
    int f  = lane & 7;         // 0..7
    for (int rl = wave; rl < CROWS; rl += 4) {
        int row = b * CROWS + rl;
        if (row >= N_NODES) continue;
        int i = st[rl], end = st[rl] + cnt[rl]; if (end > CAP) end = CAP;
        float acc0 = 0.f, acc1 = 0.f;
        for (; i + 8 <= end; i += 8) {
            int2 e0 = rec[i],     e1 = rec[i + 1], e2 = rec[i + 2], e3 = rec[i + 3];
            int2 e4 = rec[i + 4], e5 = rec[i + 5], e6 = rec[i + 6], e7 = rec[i + 7];
            uint l0 = combo[(size_t)e0.x * 16 + d0];
            uint l1 = combo[(size_t)e1.x * 16 + d0];
            uint l2 = combo[(size_t)e2.x * 16 + d0];
            uint l3 = combo[(size_t)e3.x * 16 + d0];
            uint l4 = combo[(size_t)e4.x * 16 + d0];
            uint l5 = combo[(size_t)e5.x * 16 + d0];
            uint l6 = combo[(size_t)e6.x * 16 + d0];
            uint l7 = combo[(size_t)e7.x * 16 + d0];
            uint w0 = ((const ushort*)(combo + (size_t)e0.x * 16 + 8))[f];
            uint w1 = ((const ushort*)(combo + (size_t)e1.x * 16 + 8))[f];
            uint w2 = ((const ushort*)(combo + (size_t)e2.x * 16 + 8))[f];
            uint w3 = ((const ushort*)(combo + (size_t)e3.x * 16 + 8))[f];
            uint w4 = ((const ushort*)(combo + (size_t)e4.x * 16 + 8))[f];
            uint w5 = ((const ushort*)(combo + (size_t)e5.x * 16 + 8))[f];
            uint w6 = ((const ushort*)(combo + (size_t)e6.x * 16 + 8))[f];
            uint w7 = ((const ushort*)(combo + (size_t)e7.x * 16 + 8))[f];
            float vw0 = __int_as_float(e0.y) * __uint_as_float(w0 << 16);
            float vw1 = __int_as_float(e1.y) * __uint_as_float(w1 << 16);
            float vw2 = __int_as_float(e2.y) * __uint_as_float(w2 << 16);
            float vw3 = __int_as_float(e3.y) * __uint_as_float(w3 << 16);
            float vw4 = __int_as_float(e4.y) * __uint_as_float(w4 << 16);
            float vw5 = __int_as_float(e5.y) * __uint_as_float(w5 << 16);
            float vw6 = __int_as_float(e6.y) * __uint_as_float(w6 << 16);
            float vw7 = __int_as_float(e7.y) * __uint_as_float(w7 << 16);
            acc0 = fmaf(vw0, __uint_as_float(l0 << 16), acc0);
            acc1 = fmaf(vw0, __uint_as_float(l0 & 0xFFFF0000u), acc1);
            acc0 = fmaf(vw1, __uint_as_float(l1 << 16), acc0);
            acc1 = fmaf(vw1, __uint_as_float(l1 & 0xFFFF0000u), acc1);
            acc0 = fmaf(vw2, __uint_as_float(l2 << 16), acc0);
            acc1 = fmaf(vw2, __uint_as_float(l2 & 0xFFFF0000u), acc1);
            acc0 = fmaf(vw3, __uint_as_float(l3 << 16), acc0);
            acc1 = fmaf(vw3, __uint_as_float(l3 & 0xFFFF0000u), acc1);
            acc0 = fmaf(vw4, __uint_as_float(l4 << 16), acc0);
            acc1 = fmaf(vw4, __uint_as_float(l4 & 0xFFFF0000u), acc1);
            acc0 = fmaf(vw5, __uint_as_float(l5 << 16), acc0);
            acc1 = fmaf(vw5, __uint_as_float(l5 & 0xFFFF0000u), acc1);
            acc0 = fmaf(vw6, __uint_as_float(l6 << 16), acc0);
            acc1 = fmaf(vw6, __uint_as_float(l6 & 0xFFFF0000u), acc1);
            acc0 = fmaf(vw7, __uint_as_float(l7 << 16), acc0);
            acc1 = fmaf(vw7, __uint_as_float(l7 & 0xFFFF0000u), acc1);
        }
        for (; i + 4 <= end; i += 4) {
            int2 e0 = rec[i], e1 = rec[i + 1], e2 = rec[i + 2], e3 = rec[i + 3];
            uint l0 = combo[(size_t)e0.x * 16 + d0];
            uint l1 = combo[(size_t)e1.x * 16 + d0];
            uint l2 = combo[(size_t)e2.x * 16 + d0];
            uint l3 = combo[(size_t)e3.x * 16 + d0];
            uint w0 = ((const ushort*)(combo + (size_t)e0.x * 16 + 8))[f];
            uint w1 = ((const ushort*)(combo + (size_t)e1.x * 16 + 8))[f];
            uint w2 = ((const ushort*)(combo + (size_t)e2.x * 16 + 8))[f];
            uint w3 = ((const ushort*)(combo + (size_t)e3.x * 16 + 8))[f];
            float vw0 = __int_as_float(e0.y) * __uint_as_float(w0 << 16);
            float vw1 = __int_as_float(e1.y) * __uint_as_float(w1 << 16);
            float vw2 = __int_as_float(e2.y) * __uint_as_float(w2 << 16);
            float vw3 = __int_as_float(e3.y) * __uint_as_float(w3 << 16);
            acc0 = fmaf(vw0, __uint_as_float(l0 << 16), acc0);
            acc1 = fmaf(vw0, __uint_as_float(l0 & 0xFFFF0000u), acc1);
            acc0 = fmaf(vw1, __uint_as_float(l1 << 16), acc0);
            acc1 = fmaf(vw1, __uint_as_float(l1 & 0xFFFF0000u), acc1);
            acc0 = fmaf(vw2, __uint_as_float(l2 << 16), acc0);
            acc1 = fmaf(vw2, __uint_as_float(l2 & 0xFFFF0000u), acc1);
            acc0 = fmaf(vw3, __uint_as_float(l3 << 16), acc0);
            acc1 = fmaf(vw3, __uint_as_float(l3 & 0xFFFF0000u), acc1);
        }
        for (; i < end; ++i) {
            int2 e = rec[i];
            uint l = combo[(size_t)e.x * 16 + d0];
            uint w = ((const ushort*)(combo + (size_t)e.x * 16 + 8))[f];
            float vw = __int_as_float(e.y) * __uint_as_float(w << 16);
            acc0 = fmaf(vw, __uint_as_float(l << 16), acc0);
            acc1 = fmaf(vw, __uint_as_float(l & 0xFFFF0000u), acc1);
        }
        __builtin_nontemporal_store(acc0, &out[(size_t)row * KOUT + lane]);
        __builtin_nontemporal_store(acc1, &out[(size_t)row * KOUT + 64 + lane]);
    }
}

extern "C" void kernel_launch(void* const* d_in, const int* in_sizes, int n_in,
                              void* d_out, int out_size, void* d_ws, size_t ws_size,
                              hipStream_t stream) {
    const float* x      = (const float*)d_in[0];
    const int*   L_rows = (const int*)  d_in[1];
    const int*   L_cols = (const int*)  d_in[2];
    const float* L_v    = (const float*)d_in[3];
    const float* eig    = (const float*)d_in[4];
    float* out = (float*)d_out;

    // workspace layout (~51.5 MB): combo 6.4 + regBc/regBr 13.4 each +
    // regA 18.0 + cursors 0.2. regA reused across passes (stream-ordered).
    uint* combo = (uint*)d_ws;                                // [N*16]      6.4 MB (64B/node)
    int2* regBc = (int2*)(combo + (size_t)N_NODES * 16);      // [NC1*CAP1] 13.4 MB
    int2* regBr = regBc + (size_t)NC1 * CAP1;                 // [NC1*CAP1] 13.4 MB
    int2* regA  = regBr + (size_t)NC1 * CAP1;                 // [NCB*CAP]  18.0 MB
    int*  gc1c  = (int*)(regA + (size_t)NCB * CAP);           // coarse cursors (col)
    int*  gc1r  = gc1c + NC1 * CPAD;                          // coarse cursors (row)
    int*  gfc   = gc1r + NC1 * CPAD;                          // final cursors (col)
    int*  gfr   = gfc + NCB * CPAD;                           // final cursors (row)

    hipMemsetAsync(gc1c, 0, (size_t)(2 * NC1 + 2 * NCB) * CPAD * sizeof(int), stream);

    wav_kernel<<<(N_NODES + 255) / 256, 256, 0, stream>>>(eig, combo);

    // Fused coarse binning: edges read once, both orderings produced
    binC2_kernel<<<NBLKA, 512, 0, stream>>>(L_rows, L_cols, L_v, gc1c, gc1r, regBc, regBr);

    // Pass 1: COLUMN ordering (fine bin -> fused sort+gather -> combo LTx)
    binF_kernel<<<NC1 * CHB, 512, 0, stream>>>(gc1c, regBc, gfc, regA);
    sortgather1_kernel<<<NCB, 256, 0, stream>>>(gfc, regA, x, combo);

    // Pass 2: ROW ordering (reusing regA)
    binF_kernel<<<NC1 * CHB, 512, 0, stream>>>(gc1r, regBr, gfr, regA);
    sortgather2_kernel<<<NCB, 256, 0, stream>>>(gfr, regA, combo, out);
}

// Round 13
// 254.286 us; speedup vs baseline: 1.4788x; 1.0694x over previous
//
#include <hip/hip_runtime.h>

#define N_NODES   100000
#define D_DIM     16
#define NFILT     8
#define KOUT      128
#define NNZ_CNT   1600000

// two-level binning geometry
#define SHIFT1    12
#define NC1       25                                   // coarse buckets (key>>12)
#define CAP1      67072                                // slots per coarse (mu 64000 + ~12 sigma)
#define NSUB      64                                   // sub-buckets per coarse
#define CROWS     64                                   // keys per final bucket
#define NCB       (NC1 * NSUB)                         // 1600 final buckets
#define CAP       1408                                 // final bucket slots (mu 1024 + ~12 sigma)
#define EPB       2048                                 // edges/records per bin block
#define NBLKA     ((NNZ_CNT + EPB - 1) / EPB)          // 782 coarse blocks
#define CHB       ((CAP1 + EPB - 1) / EPB)             // 33 chunks per coarse in binF
#define CPAD      16                                   // ints per cursor = one 64B line

// combo[node] = 64B line: [0..7]=LTx bf16 pairs (u32), [8..11]=wav bf16 (u16 x8).
// R10 lesson: combo beats split tables — the wav load is an L1 hit on the line
// the LTx load fetched (split = 2 independent L2 accesses; FETCH lower, dur worse).

// fp32 -> bf16 bits with round-to-nearest-even (same as __float2bfloat16)
__device__ __forceinline__ uint f32_to_bf16_bits(float f) {
    uint u = __float_as_uint(f);
    uint r = (u + 0x7FFFu + ((u >> 16) & 1u)) >> 16;
    return r;
}

// w_wav[n,f] = t^(2^f) - t^(2^(f+1)); fp32 compute, bf16 store into combo[n][8..11]
__global__ void wav_kernel(const float* __restrict__ eig, uint* __restrict__ combo) {
    int n = blockIdx.x * blockDim.x + threadIdx.x;
    if (n >= N_NODES) return;
    float cur = expf(-eig[n]);
    uint pk[4];
#pragma unroll
    for (int h = 0; h < 4; ++h) {
        float nx0 = cur * cur;
        float w0 = cur - nx0;
        float nx1 = nx0 * nx0;
        float w1 = nx0 - nx1;
        cur = nx1;
        pk[h] = f32_to_bf16_bits(w0) | (f32_to_bf16_bits(w1) << 16);
    }
    *(uint4*)(combo + (size_t)n * 16 + 8) = make_uint4(pk[0], pk[1], pk[2], pk[3]);
}

// binC2: FUSED coarse binning for both orderings (R7 measured-best version).
// Stages 2048 edges in registers ONCE, runs two phases (key=col -> regBc,
// key=row -> regBr). Runs ~82 rec = 656B -> coalesced copy-out (round-5
// lesson: scattered 8B stores cost ~100MB of line RMW).
// Record: x = ((key & 4095) << 17) | payload   (12 key bits survive to binF).
__global__ __launch_bounds__(512) void binC2_kernel(const int* __restrict__ rows,
                                                    const int* __restrict__ cols,
                                                    const float* __restrict__ v,
                                                    int* __restrict__ gc1c,
                                                    int* __restrict__ gc1r,
                                                    int2* __restrict__ regBc,
                                                    int2* __restrict__ regBr) {
    __shared__ int cnt[NC1], offb[NC1], gbase[NC1], cur[NC1];
    __shared__ int2 rec[EPB];
    __shared__ unsigned char rbk[EPB];
    int tid = threadIdx.x;
    int e0 = blockIdx.x * EPB;
    int nE = NNZ_CNT - e0; if (nE > EPB) nE = EPB;

    int r_[4], c_[4], vb_[4];
    int nk = 0;
#pragma unroll
    for (int kk = 0; kk < 4; ++kk) {
        int i = tid + kk * 512;
        if (i < nE) {
            r_[kk] = rows[e0 + i];
            c_[kk] = cols[e0 + i];
            vb_[kk] = __float_as_int(v[e0 + i]);
            nk = kk + 1;
        }
    }

    // ---- phase A: key = col, payload = row -> regBc ----
    if (tid < NC1) cnt[tid] = 0;
    __syncthreads();
    for (int kk = 0; kk < nk; ++kk) atomicAdd(&cnt[c_[kk] >> SHIFT1], 1);
    __syncthreads();
    if (tid == 0) { int run = 0; for (int b = 0; b < NC1; ++b) { offb[b] = run; run += cnt[b]; } }
    __syncthreads();
    if (tid < NC1) {
        gbase[tid] = cnt[tid] ? atomicAdd(&gc1c[tid * CPAD], cnt[tid]) : 0;
        cur[tid] = offb[tid];
    }
    __syncthreads();
    for (int kk = 0; kk < nk; ++kk) {
        int b = c_[kk] >> SHIFT1;
        int pos = atomicAdd(&cur[b], 1);
        rec[pos] = make_int2(((c_[kk] & 4095) << 17) | r_[kk], vb_[kk]);
        rbk[pos] = (unsigned char)b;
    }
    __syncthreads();
    for (int i = tid; i < nE; i += 512) {
        int b = rbk[i];
        int slot = gbase[b] + (i - offb[b]);
        if (slot < CAP1) regBc[(size_t)b * CAP1 + slot] = rec[i];
    }
    __syncthreads();

    // ---- phase B: key = row, payload = col -> regBr ----
    if (tid < NC1) cnt[tid] = 0;
    __syncthreads();
    for (int kk = 0; kk < nk; ++kk) atomicAdd(&cnt[r_[kk] >> SHIFT1], 1);
    __syncthreads();
    if (tid == 0) { int run = 0; for (int b = 0; b < NC1; ++b) { offb[b] = run; run += cnt[b]; } }
    __syncthreads();
    if (tid < NC1) {
        gbase[tid] = cnt[tid] ? atomicAdd(&gc1r[tid * CPAD], cnt[tid]) : 0;
        cur[tid] = offb[tid];
    }
    __syncthreads();
    for (int kk = 0; kk < nk; ++kk) {
        int b = r_[kk] >> SHIFT1;
        int pos = atomicAdd(&cur[b], 1);
        rec[pos] = make_int2(((r_[kk] & 4095) << 17) | c_[kk], vb_[kk]);
        rbk[pos] = (unsigned char)b;
    }
    __syncthreads();
    for (int i = tid; i < nE; i += 512) {
        int b = rbk[i];
        int slot = gbase[b] + (i - offb[b]);
        if (slot < CAP1) regBr[(size_t)b * CAP1 + slot] = rec[i];
    }
}

// binF: fine binning (unchanged control). Block = one 2048-record chunk of
// one coarse bucket; bins into 64 sub-buckets (runs ~32 rec = 256B).
// sub = record bits 23..28. Output keeps 6 low key bits:
// x = (keylow6 << 17) | payload  (mask 0x7FFFFF).
__global__ __launch_bounds__(512) void binF_kernel(const int* __restrict__ gcur1,
                                                   const int2* __restrict__ regB,
                                                   int* __restrict__ gcurF,
                                                   int2* __restrict__ regA) {
    __shared__ int cnt[NSUB], offb[NSUB], gbase[NSUB], cur[NSUB];
    __shared__ int2 rec[EPB];
    __shared__ unsigned char rbk[EPB];
    int tid = threadIdx.x;
    int cb = blockIdx.x / CHB;
    int ch = blockIdx.x % CHB;
    int nc = gcur1[cb * CPAD]; if (nc > CAP1) nc = CAP1;
    int cs = ch * EPB;
    if (cs >= nc) return;                 // uniform early-exit
    int nE = nc - cs; if (nE > EPB) nE = EPB;
    size_t srcb = (size_t)cb * CAP1 + cs;

    if (tid < NSUB) cnt[tid] = 0;
    __syncthreads();

    int2 my[4]; int msub[4];
    int nk = 0;
#pragma unroll
    for (int kk = 0; kk < 4; ++kk) {
        int i = tid + kk * 512;
        msub[kk] = -1;
        if (i < nE) {
            my[kk] = regB[srcb + i];
            msub[kk] = (my[kk].x >> 23) & (NSUB - 1);
            nk = kk + 1;
            atomicAdd(&cnt[msub[kk]], 1);
        }
    }
    __syncthreads();

    if (tid == 0) { int run = 0; for (int b = 0; b < NSUB; ++b) { offb[b] = run; run += cnt[b]; } }
    __syncthreads();
    if (tid < NSUB) {
        gbase[tid] = cnt[tid] ? atomicAdd(&gcurF[(cb * NSUB + tid) * CPAD], cnt[tid]) : 0;
        cur[tid] = offb[tid];
    }
    __syncthreads();

    for (int kk = 0; kk < nk; ++kk)
        if (msub[kk] >= 0) {
            int pos = atomicAdd(&cur[msub[kk]], 1);
            rec[pos] = make_int2(my[kk].x & 0x7FFFFF, my[kk].y);  // keylow(6) | payload(17)
            rbk[pos] = (unsigned char)msub[kk];
        }
    __syncthreads();

    for (int i = tid; i < nE; i += 512) {
        int b = rbk[i];
        int slot = gbase[b] + (i - offb[b]);
        if (slot < CAP)
            regA[(size_t)(cb * NSUB + b) * CAP + slot] = rec[i];
    }
}

// Fused sort+gather for pass 1 — now 512 threads / 8 waves per block
// (occupancy lever: 4-wave blocks left CUs at ~43% occupancy on a
// latency-bound gather; 8-wave blocks fill CUs to the 32-wave cap).
// Records -> registers + LDS histogram, scan 64, scatter into col-sorted
// LDS rec[]; then per column, 16-lane x 4-subgroup walk with REGISTER
// accumulator, unrolled x2. Per-column record order unchanged (bitwise-
// identical output). Pack bf16 pairs {d,d+8} into combo[c][0..7].
__global__ __launch_bounds__(512) void sortgather1_kernel(const int* __restrict__ gcurF,
                                                          const int2* __restrict__ regA,
                                                          const float* __restrict__ x,
                                                          uint* __restrict__ combo) {
    __shared__ int2 rec[CAP];        // 11.3 KB, col-sorted: (row, vbits)
    __shared__ int cnt[CROWS], sc[CROWS], st[CROWS], cur[CROWS];
    int tid = threadIdx.x;
    int b = blockIdx.x;
    int nb = gcurF[b * CPAD]; if (nb > CAP) nb = CAP;
    size_t base = (size_t)b * CAP;

    int2 my[3]; int mkey[3];
    if (tid < CROWS) cnt[tid] = 0;
    __syncthreads();
#pragma unroll
    for (int s = 0; s < 3; ++s) {
        int i = tid + s * 512;
        mkey[s] = -1;
        if (i < nb) {
            my[s] = regA[base + i];
            mkey[s] = my[s].x >> 17;
            atomicAdd(&cnt[mkey[s]], 1);
        }
    }
    __syncthreads();

    int cv = (tid < CROWS) ? cnt[tid] : 0;
    if (tid < CROWS) sc[tid] = cv;
    __syncthreads();
    for (int off = 1; off < CROWS; off <<= 1) {
        int t = (tid < CROWS && tid >= off) ? sc[tid - off] : 0;
        __syncthreads();
        if (tid < CROWS) sc[tid] += t;
        __syncthreads();
    }
    if (tid < CROWS) { int s0 = sc[tid] - cv; st[tid] = s0; cur[tid] = s0; }
    __syncthreads();

#pragma unroll
    for (int s = 0; s < 3; ++s)
        if (mkey[s] >= 0) {
            int pos = atomicAdd(&cur[mkey[s]], 1);
            if (pos < CAP) rec[pos] = make_int2(my[s].x & 0x1FFFF, my[s].y);
        }
    __syncthreads();

    // gather: 8 waves x 8 cols; lane = (j<<4)|d, unroll 2 (records i, i+4)
    int wave = tid >> 6, lane = tid & 63;
    int d = lane & 15, j = lane >> 4;
    for (int cl = wave; cl < CROWS; cl += 8) {
        int c = b * CROWS + cl;
        int i0 = st[cl], e0 = i0 + cnt[cl]; if (e0 > CAP) e0 = CAP;
        float acc = 0.f;
        int i = i0 + j;
        for (; i + 4 < e0; i += 8) {
            int2 ea = rec[i];
            int2 eb = rec[i + 4];
            float xa = x[(size_t)ea.x * D_DIM + d];
            float xb = x[(size_t)eb.x * D_DIM + d];
            acc = fmaf(__int_as_float(ea.y), xa, acc);
            acc = fmaf(__int_as_float(eb.y), xb, acc);
        }
        for (; i < e0; i += 4) {
            int2 e = rec[i];
            acc = fmaf(__int_as_float(e.y), x[(size_t)e.x * D_DIM + d], acc);
        }
        acc += __shfl_xor(acc, 16);
        acc += __shfl_xor(acc, 32);
        float hi = __shfl_down(acc, 8);
        if (lane < 8 && c < N_NODES)
            combo[(size_t)c * 16 + lane] =
                f32_to_bf16_bits(acc) | (f32_to_bf16_bits(hi) << 16);
    }
}

// Fused sort+gather for pass 2 — now 512 threads / 8 waves per block (same
// occupancy lever; measured 43% occupancy at 4 waves/block was the limiter
// after the x8 unroll saturated per-wave MLP). Reg-staged LDS sort; gather
// reads ONE combo line per record (wav is an L1 hit on the LTx line),
// unrolled x8. Per-row record order unchanged (bitwise-identical). out
// stores nontemporal.
__global__ __launch_bounds__(512) void sortgather2_kernel(const int* __restrict__ gcurF,
                                                          const int2* __restrict__ regA,
                                                          const uint* __restrict__ combo,
                                                          float* __restrict__ out) {
    __shared__ int2 rec[CAP];        // 11.3 KB, row-sorted: (col, vbits)
    __shared__ int cnt[CROWS], sc[CROWS], st[CROWS], cur[CROWS];
    int tid = threadIdx.x;
    int b = blockIdx.x;
    int nb = gcurF[b * CPAD]; if (nb > CAP) nb = CAP;
    size_t base = (size_t)b * CAP;

    int2 my[3]; int mkey[3];
    if (tid < CROWS) cnt[tid] = 0;
    __syncthreads();
#pragma unroll
    for (int s = 0; s < 3; ++s) {
        int i = tid + s * 512;
        mkey[s] = -1;
        if (i < nb) {
            my[s] = regA[base + i];
            mkey[s] = my[s].x >> 17;
            atomicAdd(&cnt[mkey[s]], 1);
        }
    }
    __syncthreads();

    int cv = (tid < CROWS) ? cnt[tid] : 0;
    if (tid < CROWS) sc[tid] = cv;
    __syncthreads();
    for (int off = 1; off < CROWS; off <<= 1) {
        int t = (tid < CROWS && tid >= off) ? sc[tid - off] : 0;
        __syncthreads();
        if (tid < CROWS) sc[tid] += t;
        __syncthreads();
    }
    if (tid < CROWS) { int s0 = sc[tid] - cv; st[tid] = s0; cur[tid] = s0; }
    __syncthreads();

#pragma unroll
    for (int s = 0; s < 3; ++s)
        if (mkey[s] >= 0) {
            int pos = atomicAdd(&cur[mkey[s]], 1);
            if (pos < CAP) rec[pos] = make_int2(my[s].x & 0x1FFFF, my[s].y);
        }
    __syncthreads();

    // gather: 8 waves x 8 rows; lane owns outputs (lane) and (lane+64)
    int wave = tid >> 6, lane = tid & 63;
    int d0 = lane >> 3;        // pair index 0..7
    int f  = lane & 7;         // 0..7
    for (int rl = wave; rl < CROWS; rl += 8) {
        int row = b * CROWS + rl;
        if (row >= N_NODES) continue;
        int i = st[rl], end = st[rl] + cnt[rl]; if (end > CAP) end = CAP;
        float acc0 = 0.f, acc1 = 0.f;
        for (; i + 8 <= end; i += 8) {
            int2 e0 = rec[i],     e1 = rec[i + 1], e2 = rec[i + 2], e3 = rec[i + 3];
            int2 e4 = rec[i + 4], e5 = rec[i + 5], e6 = rec[i + 6], e7 = rec[i + 7];
            uint l0 = combo[(size_t)e0.x * 16 + d0];
            uint l1 = combo[(size_t)e1.x * 16 + d0];
            uint l2 = combo[(size_t)e2.x * 16 + d0];
            uint l3 = combo[(size_t)e3.x * 16 + d0];
            uint l4 = combo[(size_t)e4.x * 16 + d0];
            uint l5 = combo[(size_t)e5.x * 16 + d0];
            uint l6 = combo[(size_t)e6.x * 16 + d0];
            uint l7 = combo[(size_t)e7.x * 16 + d0];
            uint w0 = ((const ushort*)(combo + (size_t)e0.x * 16 + 8))[f];
            uint w1 = ((const ushort*)(combo + (size_t)e1.x * 16 + 8))[f];
            uint w2 = ((const ushort*)(combo + (size_t)e2.x * 16 + 8))[f];
            uint w3 = ((const ushort*)(combo + (size_t)e3.x * 16 + 8))[f];
            uint w4 = ((const ushort*)(combo + (size_t)e4.x * 16 + 8))[f];
            uint w5 = ((const ushort*)(combo + (size_t)e5.x * 16 + 8))[f];
            uint w6 = ((const ushort*)(combo + (size_t)e6.x * 16 + 8))[f];
            uint w7 = ((const ushort*)(combo + (size_t)e7.x * 16 + 8))[f];
            float vw0 = __int_as_float(e0.y) * __uint_as_float(w0 << 16);
            float vw1 = __int_as_float(e1.y) * __uint_as_float(w1 << 16);
            float vw2 = __int_as_float(e2.y) * __uint_as_float(w2 << 16);
            float vw3 = __int_as_float(e3.y) * __uint_as_float(w3 << 16);
            float vw4 = __int_as_float(e4.y) * __uint_as_float(w4 << 16);
            float vw5 = __int_as_float(e5.y) * __uint_as_float(w5 << 16);
            float vw6 = __int_as_float(e6.y) * __uint_as_float(w6 << 16);
            float vw7 = __int_as_float(e7.y) * __uint_as_float(w7 << 16);
            acc0 = fmaf(vw0, __uint_as_float(l0 << 16), acc0);
            acc1 = fmaf(vw0, __uint_as_float(l0 & 0xFFFF0000u), acc1);
            acc0 = fmaf(vw1, __uint_as_float(l1 << 16), acc0);
            acc1 = fmaf(vw1, __uint_as_float(l1 & 0xFFFF0000u), acc1);
            acc0 = fmaf(vw2, __uint_as_float(l2 << 16), acc0);
            acc1 = fmaf(vw2, __uint_as_float(l2 & 0xFFFF0000u), acc1);
            acc0 = fmaf(vw3, __uint_as_float(l3 << 16), acc0);
            acc1 = fmaf(vw3, __uint_as_float(l3 & 0xFFFF0000u), acc1);
            acc0 = fmaf(vw4, __uint_as_float(l4 << 16), acc0);
            acc1 = fmaf(vw4, __uint_as_float(l4 & 0xFFFF0000u), acc1);
            acc0 = fmaf(vw5, __uint_as_float(l5 << 16), acc0);
            acc1 = fmaf(vw5, __uint_as_float(l5 & 0xFFFF0000u), acc1);
            acc0 = fmaf(vw6, __uint_as_float(l6 << 16), acc0);
            acc1 = fmaf(vw6, __uint_as_float(l6 & 0xFFFF0000u), acc1);
            acc0 = fmaf(vw7, __uint_as_float(l7 << 16), acc0);
            acc1 = fmaf(vw7, __uint_as_float(l7 & 0xFFFF0000u), acc1);
        }
        for (; i + 4 <= end; i += 4) {
            int2 e0 = rec[i], e1 = rec[i + 1], e2 = rec[i + 2], e3 = rec[i + 3];
            uint l0 = combo[(size_t)e0.x * 16 + d0];
            uint l1 = combo[(size_t)e1.x * 16 + d0];
            uint l2 = combo[(size_t)e2.x * 16 + d0];
            uint l3 = combo[(size_t)e3.x * 16 + d0];
            uint w0 = ((const ushort*)(combo + (size_t)e0.x * 16 + 8))[f];
            uint w1 = ((const ushort*)(combo + (size_t)e1.x * 16 + 8))[f];
            uint w2 = ((const ushort*)(combo + (size_t)e2.x * 16 + 8))[f];
            uint w3 = ((const ushort*)(combo + (size_t)e3.x * 16 + 8))[f];
            float vw0 = __int_as_float(e0.y) * __uint_as_float(w0 << 16);
            float vw1 = __int_as_float(e1.y) * __uint_as_float(w1 << 16);
            float vw2 = __int_as_float(e2.y) * __uint_as_float(w2 << 16);
            float vw3 = __int_as_float(e3.y) * __uint_as_float(w3 << 16);
            acc0 = fmaf(vw0, __uint_as_float(l0 << 16), acc0);
            acc1 = fmaf(vw0, __uint_as_float(l0 & 0xFFFF0000u), acc1);
            acc0 = fmaf(vw1, __uint_as_float(l1 << 16), acc0);
            acc1 = fmaf(vw1, __uint_as_float(l1 & 0xFFFF0000u), acc1);
            acc0 = fmaf(vw2, __uint_as_float(l2 << 16), acc0);
            acc1 = fmaf(vw2, __uint_as_float(l2 & 0xFFFF0000u), acc1);
            acc0 = fmaf(vw3, __uint_as_float(l3 << 16), acc0);
            acc1 = fmaf(vw3, __uint_as_float(l3 & 0xFFFF0000u), acc1);
        }
        for (; i < end; ++i) {
            int2 e = rec[i];
            uint l = combo[(size_t)e.x * 16 + d0];
            uint w = ((const ushort*)(combo + (size_t)e.x * 16 + 8))[f];
            float vw = __int_as_float(e.y) * __uint_as_float(w << 16);
            acc0 = fmaf(vw, __uint_as_float(l << 16), acc0);
            acc1 = fmaf(vw, __uint_as_float(l & 0xFFFF0000u), acc1);
        }
        __builtin_nontemporal_store(acc0, &out[(size_t)row * KOUT + lane]);
        __builtin_nontemporal_store(acc1, &out[(size_t)row * KOUT + 64 + lane]);
    }
}

extern "C" void kernel_launch(void* const* d_in, const int* in_sizes, int n_in,
                              void* d_out, int out_size, void* d_ws, size_t ws_size,
                              hipStream_t stream) {
    const float* x      = (const float*)d_in[0];
    const int*   L_rows = (const int*)  d_in[1];
    const int*   L_cols = (const int*)  d_in[2];
    const float* L_v    = (const float*)d_in[3];
    const float* eig    = (const float*)d_in[4];
    float* out = (float*)d_out;

    // workspace layout (~51.5 MB): combo 6.4 + regBc/regBr 13.4 each +
    // regA 18.0 + cursors 0.2. regA reused across passes (stream-ordered).
    uint* combo = (uint*)d_ws;                                // [N*16]      6.4 MB (64B/node)
    int2* regBc = (int2*)(combo + (size_t)N_NODES * 16);      // [NC1*CAP1] 13.4 MB
    int2* regBr = regBc + (size_t)NC1 * CAP1;                 // [NC1*CAP1] 13.4 MB
    int2* regA  = regBr + (size_t)NC1 * CAP1;                 // [NCB*CAP]  18.0 MB
    int*  gc1c  = (int*)(regA + (size_t)NCB * CAP);           // coarse cursors (col)
    int*  gc1r  = gc1c + NC1 * CPAD;                          // coarse cursors (row)
    int*  gfc   = gc1r + NC1 * CPAD;                          // final cursors (col)
    int*  gfr   = gfc + NCB * CPAD;                           // final cursors (row)

    hipMemsetAsync(gc1c, 0, (size_t)(2 * NC1 + 2 * NCB) * CPAD * sizeof(int), stream);

    wav_kernel<<<(N_NODES + 255) / 256, 256, 0, stream>>>(eig, combo);

    // Fused coarse binning: edges read once, both orderings produced
    binC2_kernel<<<NBLKA, 512, 0, stream>>>(L_rows, L_cols, L_v, gc1c, gc1r, regBc, regBr);

    // Pass 1: COLUMN ordering (fine bin -> fused sort+gather -> combo LTx)
    binF_kernel<<<NC1 * CHB, 512, 0, stream>>>(gc1c, regBc, gfc, regA);
    sortgather1_kernel<<<NCB, 512, 0, stream>>>(gfc, regA, x, combo);

    // Pass 2: ROW ordering (reusing regA)
    binF_kernel<<<NC1 * CHB, 512, 0, stream>>>(gc1r, regBr, gfr, regA);
    sortgather2_kernel<<<NCB, 512, 0, stream>>>(gfr, regA, combo, out);
}

// Round 14
// 247.922 us; speedup vs baseline: 1.5168x; 1.0257x over previous
//
#include <hip/hip_runtime.h>

#define N_NODES   100000
#define D_DIM     16
#define NFILT     8
#define KOUT      128
#define NNZ_CNT   1600000

// two-level binning geometry
#define SHIFT1    12
#define NC1       25                                   // coarse buckets (key>>12)
#define CAP1      67072                                // slots per coarse (mu 64000 + ~12 sigma)
#define NSUB      64                                   // sub-buckets per coarse
#define CROWS     64                                   // keys per final bucket
#define NCB       (NC1 * NSUB)                         // 1600 final buckets
#define CAP       1408                                 // final bucket slots (mu 1024 + ~12 sigma)
#define EPB       2048                                 // edges/records per bin block
#define NBLKA     ((NNZ_CNT + EPB - 1) / EPB)          // 782 coarse blocks
#define CHB       ((CAP1 + EPB - 1) / EPB)             // 33 chunks per coarse in binF
#define CPAD      16                                   // ints per cursor = one 64B line

// Gather-table design (R13->R14): the 6.4MB combo line overflowed the 4MiB
// per-XCD L2 (~40MB of refetch, 1.7TB/s plateau). wav is now RECOMPUTED
// in-register from eig (a = __expf(-eig*2^f); wav = a - a^2), so the gather
// working set is LTxA 3.2MB + eig 0.4MB = 3.6MB < 4MiB -> L2-resident.
// (R10's 4.8MB split pair missed; 3.6MB is the first config that fits.)

// fp32 -> bf16 bits with round-to-nearest-even (same as __float2bfloat16)
__device__ __forceinline__ uint f32_to_bf16_bits(float f) {
    uint u = __float_as_uint(f);
    uint r = (u + 0x7FFFu + ((u >> 16) & 1u)) >> 16;
    return r;
}

// binC2: FUSED coarse binning for both orderings (R7 measured-best version).
// Stages 2048 edges in registers ONCE, runs two phases (key=col -> regBc,
// key=row -> regBr). Runs ~82 rec = 656B -> coalesced copy-out (round-5
// lesson: scattered 8B stores cost ~100MB of line RMW).
// Record: x = ((key & 4095) << 17) | payload   (12 key bits survive to binF).
__global__ __launch_bounds__(512) void binC2_kernel(const int* __restrict__ rows,
                                                    const int* __restrict__ cols,
                                                    const float* __restrict__ v,
                                                    int* __restrict__ gc1c,
                                                    int* __restrict__ gc1r,
                                                    int2* __restrict__ regBc,
                                                    int2* __restrict__ regBr) {
    __shared__ int cnt[NC1], offb[NC1], gbase[NC1], cur[NC1];
    __shared__ int2 rec[EPB];
    __shared__ unsigned char rbk[EPB];
    int tid = threadIdx.x;
    int e0 = blockIdx.x * EPB;
    int nE = NNZ_CNT - e0; if (nE > EPB) nE = EPB;

    int r_[4], c_[4], vb_[4];
    int nk = 0;
#pragma unroll
    for (int kk = 0; kk < 4; ++kk) {
        int i = tid + kk * 512;
        if (i < nE) {
            r_[kk] = rows[e0 + i];
            c_[kk] = cols[e0 + i];
            vb_[kk] = __float_as_int(v[e0 + i]);
            nk = kk + 1;
        }
    }

    // ---- phase A: key = col, payload = row -> regBc ----
    if (tid < NC1) cnt[tid] = 0;
    __syncthreads();
    for (int kk = 0; kk < nk; ++kk) atomicAdd(&cnt[c_[kk] >> SHIFT1], 1);
    __syncthreads();
    if (tid == 0) { int run = 0; for (int b = 0; b < NC1; ++b) { offb[b] = run; run += cnt[b]; } }
    __syncthreads();
    if (tid < NC1) {
        gbase[tid] = cnt[tid] ? atomicAdd(&gc1c[tid * CPAD], cnt[tid]) : 0;
        cur[tid] = offb[tid];
    }
    __syncthreads();
    for (int kk = 0; kk < nk; ++kk) {
        int b = c_[kk] >> SHIFT1;
        int pos = atomicAdd(&cur[b], 1);
        rec[pos] = make_int2(((c_[kk] & 4095) << 17) | r_[kk], vb_[kk]);
        rbk[pos] = (unsigned char)b;
    }
    __syncthreads();
    for (int i = tid; i < nE; i += 512) {
        int b = rbk[i];
        int slot = gbase[b] + (i - offb[b]);
        if (slot < CAP1) regBc[(size_t)b * CAP1 + slot] = rec[i];
    }
    __syncthreads();

    // ---- phase B: key = row, payload = col -> regBr ----
    if (tid < NC1) cnt[tid] = 0;
    __syncthreads();
    for (int kk = 0; kk < nk; ++kk) atomicAdd(&cnt[r_[kk] >> SHIFT1], 1);
    __syncthreads();
    if (tid == 0) { int run = 0; for (int b = 0; b < NC1; ++b) { offb[b] = run; run += cnt[b]; } }
    __syncthreads();
    if (tid < NC1) {
        gbase[tid] = cnt[tid] ? atomicAdd(&gc1r[tid * CPAD], cnt[tid]) : 0;
        cur[tid] = offb[tid];
    }
    __syncthreads();
    for (int kk = 0; kk < nk; ++kk) {
        int b = r_[kk] >> SHIFT1;
        int pos = atomicAdd(&cur[b], 1);
        rec[pos] = make_int2(((r_[kk] & 4095) << 17) | c_[kk], vb_[kk]);
        rbk[pos] = (unsigned char)b;
    }
    __syncthreads();
    for (int i = tid; i < nE; i += 512) {
        int b = rbk[i];
        int slot = gbase[b] + (i - offb[b]);
        if (slot < CAP1) regBr[(size_t)b * CAP1 + slot] = rec[i];
    }
}

// binF: fine binning (unchanged control). Block = one 2048-record chunk of
// one coarse bucket; bins into 64 sub-buckets (runs ~32 rec = 256B).
// sub = record bits 23..28. Output keeps 6 low key bits:
// x = (keylow6 << 17) | payload  (mask 0x7FFFFF).
__global__ __launch_bounds__(512) void binF_kernel(const int* __restrict__ gcur1,
                                                   const int2* __restrict__ regB,
                                                   int* __restrict__ gcurF,
                                                   int2* __restrict__ regA) {
    __shared__ int cnt[NSUB], offb[NSUB], gbase[NSUB], cur[NSUB];
    __shared__ int2 rec[EPB];
    __shared__ unsigned char rbk[EPB];
    int tid = threadIdx.x;
    int cb = blockIdx.x / CHB;
    int ch = blockIdx.x % CHB;
    int nc = gcur1[cb * CPAD]; if (nc > CAP1) nc = CAP1;
    int cs = ch * EPB;
    if (cs >= nc) return;                 // uniform early-exit
    int nE = nc - cs; if (nE > EPB) nE = EPB;
    size_t srcb = (size_t)cb * CAP1 + cs;

    if (tid < NSUB) cnt[tid] = 0;
    __syncthreads();

    int2 my[4]; int msub[4];
    int nk = 0;
#pragma unroll
    for (int kk = 0; kk < 4; ++kk) {
        int i = tid + kk * 512;
        msub[kk] = -1;
        if (i < nE) {
            my[kk] = regB[srcb + i];
            msub[kk] = (my[kk].x >> 23) & (NSUB - 1);
            nk = kk + 1;
            atomicAdd(&cnt[msub[kk]], 1);
        }
    }
    __syncthreads();

    if (tid == 0) { int run = 0; for (int b = 0; b < NSUB; ++b) { offb[b] = run; run += cnt[b]; } }
    __syncthreads();
    if (tid < NSUB) {
        gbase[tid] = cnt[tid] ? atomicAdd(&gcurF[(cb * NSUB + tid) * CPAD], cnt[tid]) : 0;
        cur[tid] = offb[tid];
    }
    __syncthreads();

    for (int kk = 0; kk < nk; ++kk)
        if (msub[kk] >= 0) {
            int pos = atomicAdd(&cur[msub[kk]], 1);
            rec[pos] = make_int2(my[kk].x & 0x7FFFFF, my[kk].y);  // keylow(6) | payload(17)
            rbk[pos] = (unsigned char)msub[kk];
        }
    __syncthreads();

    for (int i = tid; i < nE; i += 512) {
        int b = rbk[i];
        int slot = gbase[b] + (i - offb[b]);
        if (slot < CAP)
            regA[(size_t)(cb * NSUB + b) * CAP + slot] = rec[i];
    }
}

// Fused sort+gather for pass 1 (R13 structure, 512 thr / 8 waves).
// Records -> registers + LDS histogram, scan 64, scatter into col-sorted
// LDS rec[]; then per column, 16-lane x 4-subgroup walk with REGISTER
// accumulator, unrolled x2. Pack bf16 pairs {d,d+8} into LTxA[c*8..c*8+7]
// (32B/node -> gather table L2-fits in pass 2).
__global__ __launch_bounds__(512) void sortgather1_kernel(const int* __restrict__ gcurF,
                                                          const int2* __restrict__ regA,
                                                          const float* __restrict__ x,
                                                          uint* __restrict__ LTxA) {
    __shared__ int2 rec[CAP];        // 11.3 KB, col-sorted: (row, vbits)
    __shared__ int cnt[CROWS], sc[CROWS], st[CROWS], cur[CROWS];
    int tid = threadIdx.x;
    int b = blockIdx.x;
    int nb = gcurF[b * CPAD]; if (nb > CAP) nb = CAP;
    size_t base = (size_t)b * CAP;

    int2 my[3]; int mkey[3];
    if (tid < CROWS) cnt[tid] = 0;
    __syncthreads();
#pragma unroll
    for (int s = 0; s < 3; ++s) {
        int i = tid + s * 512;
        mkey[s] = -1;
        if (i < nb) {
            my[s] = regA[base + i];
            mkey[s] = my[s].x >> 17;
            atomicAdd(&cnt[mkey[s]], 1);
        }
    }
    __syncthreads();

    int cv = (tid < CROWS) ? cnt[tid] : 0;
    if (tid < CROWS) sc[tid] = cv;
    __syncthreads();
    for (int off = 1; off < CROWS; off <<= 1) {
        int t = (tid < CROWS && tid >= off) ? sc[tid - off] : 0;
        __syncthreads();
        if (tid < CROWS) sc[tid] += t;
        __syncthreads();
    }
    if (tid < CROWS) { int s0 = sc[tid] - cv; st[tid] = s0; cur[tid] = s0; }
    __syncthreads();

#pragma unroll
    for (int s = 0; s < 3; ++s)
        if (mkey[s] >= 0) {
            int pos = atomicAdd(&cur[mkey[s]], 1);
            if (pos < CAP) rec[pos] = make_int2(my[s].x & 0x1FFFF, my[s].y);
        }
    __syncthreads();

    // gather: 8 waves x 8 cols; lane = (j<<4)|d, unroll 2 (records i, i+4)
    int wave = tid >> 6, lane = tid & 63;
    int d = lane & 15, j = lane >> 4;
    for (int cl = wave; cl < CROWS; cl += 8) {
        int c = b * CROWS + cl;
        int i0 = st[cl], e0 = i0 + cnt[cl]; if (e0 > CAP) e0 = CAP;
        float acc = 0.f;
        int i = i0 + j;
        for (; i + 4 < e0; i += 8) {
            int2 ea = rec[i];
            int2 eb = rec[i + 4];
            float xa = x[(size_t)ea.x * D_DIM + d];
            float xb = x[(size_t)eb.x * D_DIM + d];
            acc = fmaf(__int_as_float(ea.y), xa, acc);
            acc = fmaf(__int_as_float(eb.y), xb, acc);
        }
        for (; i < e0; i += 4) {
            int2 e = rec[i];
            acc = fmaf(__int_as_float(e.y), x[(size_t)e.x * D_DIM + d], acc);
        }
        acc += __shfl_xor(acc, 16);
        acc += __shfl_xor(acc, 32);
        float hi = __shfl_down(acc, 8);
        if (lane < 8 && c < N_NODES)
            LTxA[(size_t)c * NFILT + lane] =
                f32_to_bf16_bits(acc) | (f32_to_bf16_bits(hi) << 16);
    }
}

// Fused sort+gather for pass 2 (R13 geometry, 512 thr). Gather reads LTxA
// (3.2MB) + eig (0.4MB) -- both L2-resident -- and recomputes wav in-register:
//   a = __expf(-eig * 2^f);  wav = a - a^2 = fmaf(-a, a, a)
// (t^(2^f) = exp(-eig*2^f) = a; t^(2^(f+1)) = a^2). fp32 wav (was bf16) ->
// numerics improve slightly; absmax still dominated by bf16 LTx. eig loads
// are wave-broadcast (all 64 lanes same address). Unroll x8 retained. out
// stores nontemporal (bypass L2, protect the gather tables).
__global__ __launch_bounds__(512) void sortgather2_kernel(const int* __restrict__ gcurF,
                                                          const int2* __restrict__ regA,
                                                          const uint* __restrict__ LTxA,
                                                          const float* __restrict__ eig,
                                                          float* __restrict__ out) {
    __shared__ int2 rec[CAP];        // 11.3 KB, row-sorted: (col, vbits)
    __shared__ int cnt[CROWS], sc[CROWS], st[CROWS], cur[CROWS];
    int tid = threadIdx.x;
    int b = blockIdx.x;
    int nb = gcurF[b * CPAD]; if (nb > CAP) nb = CAP;
    size_t base = (size_t)b * CAP;

    int2 my[3]; int mkey[3];
    if (tid < CROWS) cnt[tid] = 0;
    __syncthreads();
#pragma unroll
    for (int s = 0; s < 3; ++s) {
        int i = tid + s * 512;
        mkey[s] = -1;
        if (i < nb) {
            my[s] = regA[base + i];
            mkey[s] = my[s].x >> 17;
            atomicAdd(&cnt[mkey[s]], 1);
        }
    }
    __syncthreads();

    int cv = (tid < CROWS) ? cnt[tid] : 0;
    if (tid < CROWS) sc[tid] = cv;
    __syncthreads();
    for (int off = 1; off < CROWS; off <<= 1) {
        int t = (tid < CROWS && tid >= off) ? sc[tid - off] : 0;
        __syncthreads();
        if (tid < CROWS) sc[tid] += t;
        __syncthreads();
    }
    if (tid < CROWS) { int s0 = sc[tid] - cv; st[tid] = s0; cur[tid] = s0; }
    __syncthreads();

#pragma unroll
    for (int s = 0; s < 3; ++s)
        if (mkey[s] >= 0) {
            int pos = atomicAdd(&cur[mkey[s]], 1);
            if (pos < CAP) rec[pos] = make_int2(my[s].x & 0x1FFFF, my[s].y);
        }
    __syncthreads();

    // gather: 8 waves x 8 rows; lane owns outputs (lane) and (lane+64)
    int wave = tid >> 6, lane = tid & 63;
    int d0 = lane >> 3;                  // pair index 0..7
    int f  = lane & 7;                   // 0..7
    float fscale = (float)(1 << f);      // 2^f (per-lane constant)
    for (int rl = wave; rl < CROWS; rl += 8) {
        int row = b * CROWS + rl;
        if (row >= N_NODES) continue;
        int i = st[rl], end = st[rl] + cnt[rl]; if (end > CAP) end = CAP;
        float acc0 = 0.f, acc1 = 0.f;
        for (; i + 8 <= end; i += 8) {
            int2 e0 = rec[i],     e1 = rec[i + 1], e2 = rec[i + 2], e3 = rec[i + 3];
            int2 e4 = rec[i + 4], e5 = rec[i + 5], e6 = rec[i + 6], e7 = rec[i + 7];
            uint l0 = LTxA[(size_t)e0.x * NFILT + d0];
            uint l1 = LTxA[(size_t)e1.x * NFILT + d0];
            uint l2 = LTxA[(size_t)e2.x * NFILT + d0];
            uint l3 = LTxA[(size_t)e3.x * NFILT + d0];
            uint l4 = LTxA[(size_t)e4.x * NFILT + d0];
            uint l5 = LTxA[(size_t)e5.x * NFILT + d0];
            uint l6 = LTxA[(size_t)e6.x * NFILT + d0];
            uint l7 = LTxA[(size_t)e7.x * NFILT + d0];
            float g0 = eig[e0.x], g1 = eig[e1.x], g2 = eig[e2.x], g3 = eig[e3.x];
            float g4 = eig[e4.x], g5 = eig[e5.x], g6 = eig[e6.x], g7 = eig[e7.x];
            float a0 = __expf(-g0 * fscale), a1 = __expf(-g1 * fscale);
            float a2 = __expf(-g2 * fscale), a3 = __expf(-g3 * fscale);
            float a4 = __expf(-g4 * fscale), a5 = __expf(-g5 * fscale);
            float a6 = __expf(-g6 * fscale), a7 = __expf(-g7 * fscale);
            float vw0 = __int_as_float(e0.y) * fmaf(-a0, a0, a0);
            float vw1 = __int_as_float(e1.y) * fmaf(-a1, a1, a1);
            float vw2 = __int_as_float(e2.y) * fmaf(-a2, a2, a2);
            float vw3 = __int_as_float(e3.y) * fmaf(-a3, a3, a3);
            float vw4 = __int_as_float(e4.y) * fmaf(-a4, a4, a4);
            float vw5 = __int_as_float(e5.y) * fmaf(-a5, a5, a5);
            float vw6 = __int_as_float(e6.y) * fmaf(-a6, a6, a6);
            float vw7 = __int_as_float(e7.y) * fmaf(-a7, a7, a7);
            acc0 = fmaf(vw0, __uint_as_float(l0 << 16), acc0);
            acc1 = fmaf(vw0, __uint_as_float(l0 & 0xFFFF0000u), acc1);
            acc0 = fmaf(vw1, __uint_as_float(l1 << 16), acc0);
            acc1 = fmaf(vw1, __uint_as_float(l1 & 0xFFFF0000u), acc1);
            acc0 = fmaf(vw2, __uint_as_float(l2 << 16), acc0);
            acc1 = fmaf(vw2, __uint_as_float(l2 & 0xFFFF0000u), acc1);
            acc0 = fmaf(vw3, __uint_as_float(l3 << 16), acc0);
            acc1 = fmaf(vw3, __uint_as_float(l3 & 0xFFFF0000u), acc1);
            acc0 = fmaf(vw4, __uint_as_float(l4 << 16), acc0);
            acc1 = fmaf(vw4, __uint_as_float(l4 & 0xFFFF0000u), acc1);
            acc0 = fmaf(vw5, __uint_as_float(l5 << 16), acc0);
            acc1 = fmaf(vw5, __uint_as_float(l5 & 0xFFFF0000u), acc1);
            acc0 = fmaf(vw6, __uint_as_float(l6 << 16), acc0);
            acc1 = fmaf(vw6, __uint_as_float(l6 & 0xFFFF0000u), acc1);
            acc0 = fmaf(vw7, __uint_as_float(l7 << 16), acc0);
            acc1 = fmaf(vw7, __uint_as_float(l7 & 0xFFFF0000u), acc1);
        }
        for (; i < end; ++i) {
            int2 e = rec[i];
            uint l = LTxA[(size_t)e.x * NFILT + d0];
            float g = eig[e.x];
            float a = __expf(-g * fscale);
            float vw = __int_as_float(e.y) * fmaf(-a, a, a);
            acc0 = fmaf(vw, __uint_as_float(l << 16), acc0);
            acc1 = fmaf(vw, __uint_as_float(l & 0xFFFF0000u), acc1);
        }
        __builtin_nontemporal_store(acc0, &out[(size_t)row * KOUT + lane]);
        __builtin_nontemporal_store(acc1, &out[(size_t)row * KOUT + 64 + lane]);
    }
}

extern "C" void kernel_launch(void* const* d_in, const int* in_sizes, int n_in,
                              void* d_out, int out_size, void* d_ws, size_t ws_size,
                              hipStream_t stream) {
    const float* x      = (const float*)d_in[0];
    const int*   L_rows = (const int*)  d_in[1];
    const int*   L_cols = (const int*)  d_in[2];
    const float* L_v    = (const float*)d_in[3];
    const float* eig    = (const float*)d_in[4];
    float* out = (float*)d_out;

    // workspace layout (~48.2 MB): LTxA 3.2 + regBc/regBr 13.4 each +
    // regA 18.0 + cursors 0.2. regA reused across passes (stream-ordered).
    uint* LTxA  = (uint*)d_ws;                                // [N*8]       3.2 MB (bf16 pairs)
    int2* regBc = (int2*)(LTxA + (size_t)N_NODES * NFILT);    // [NC1*CAP1] 13.4 MB
    int2* regBr = regBc + (size_t)NC1 * CAP1;                 // [NC1*CAP1] 13.4 MB
    int2* regA  = regBr + (size_t)NC1 * CAP1;                 // [NCB*CAP]  18.0 MB
    int*  gc1c  = (int*)(regA + (size_t)NCB * CAP);           // coarse cursors (col)
    int*  gc1r  = gc1c + NC1 * CPAD;                          // coarse cursors (row)
    int*  gfc   = gc1r + NC1 * CPAD;                          // final cursors (col)
    int*  gfr   = gfc + NCB * CPAD;                           // final cursors (row)

    hipMemsetAsync(gc1c, 0, (size_t)(2 * NC1 + 2 * NCB) * CPAD * sizeof(int), stream);

    // Fused coarse binning: edges read once, both orderings produced
    binC2_kernel<<<NBLKA, 512, 0, stream>>>(L_rows, L_cols, L_v, gc1c, gc1r, regBc, regBr);

    // Pass 1: COLUMN ordering (fine bin -> fused sort+gather -> bf16 LTxA)
    binF_kernel<<<NC1 * CHB, 512, 0, stream>>>(gc1c, regBc, gfc, regA);
    sortgather1_kernel<<<NCB, 512, 0, stream>>>(gfc, regA, x, LTxA);

    // Pass 2: ROW ordering (reusing regA); wav recomputed in-register
    binF_kernel<<<NC1 * CHB, 512, 0, stream>>>(gc1r, regBr, gfr, regA);
    sortgather2_kernel<<<NCB, 512, 0, stream>>>(gfr, regA, LTxA, eig, out);
}